// Round 1
// baseline (982.936 us; speedup 1.0000x reference)
//
#include <hip/hip_runtime.h>
#include <math.h>

// ---------------- ws layout (floats) ----------------
static const size_t OFF_POOLED = 0;                     // 2048*90
static const size_t OFF_EMB1   = 184320;                // 2048*4096 (reused for fe1)
static const size_t OFF_ACC1   = OFF_EMB1 + 8388608;    // 2048*64
static const size_t OFF_ACC2   = OFF_ACC1 + 131072;     // 2048*64
static const size_t OFF_X1     = OFF_ACC2 + 131072;     // 2048*256
static const size_t OFF_FPOOL  = OFF_X1 + 524288;       // 2048*90
static const size_t OFF_H1     = OFF_FPOOL + 184320;    // 2048*64
static const size_t OFF_C1     = OFF_H1 + 131072;       // 2048*64
static const size_t OFF_H2     = OFF_C1 + 131072;       // 2048*32
static const size_t OFF_C2     = OFF_H2 + 65536;        // 2048*32
// total = 9,936,896 floats ≈ 39.75 MB

__device__ __forceinline__ float sigf(float x) { return 1.0f / (1.0f + expf(-x)); }

// ---------------- SPP: adaptive max pool levels 4,3,2,1 ----------------
// one block per (img, channel); plane staged in LDS.
__global__ __launch_bounds__(256) void spp_kernel(const float* __restrict__ frames,
                                                  float* __restrict__ out_pooled,
                                                  float* __restrict__ ws_pooled) {
    __shared__ __align__(16) float img[9216];
    __shared__ float p4[16], p3[9];
    int blk = blockIdx.x;          // n*3 + c
    int n = blk / 3, c = blk % 3;
    const float* src = frames + (size_t)blk * 9216;
    int tid = threadIdx.x;
    const float4* s4 = (const float4*)src;
    float4* i4 = (float4*)img;
#pragma unroll
    for (int j = 0; j < 9; ++j) i4[tid + 256 * j] = s4[tid + 256 * j];
    __syncthreads();
    // level 4: 16 regions of 24x24, 16 threads each
    {
        int r = tid >> 4, i = tid & 15;
        int ri = r >> 2, rj = r & 3;
        float m = -3.402823466e38f;
        for (int rr = i; rr < 24; rr += 16) {
            const float4* rowp = (const float4*)&img[(24 * ri + rr) * 96 + 24 * rj];
#pragma unroll
            for (int q = 0; q < 6; ++q) {
                float4 v = rowp[q];
                m = fmaxf(m, fmaxf(fmaxf(v.x, v.y), fmaxf(v.z, v.w)));
            }
        }
#pragma unroll
        for (int sh = 8; sh >= 1; sh >>= 1) m = fmaxf(m, __shfl_xor(m, sh));
        if (i == 0) p4[r] = m;
    }
    // level 3: 9 regions of 32x32, 16 threads each
    if (tid < 144) {
        int r = tid >> 4, i = tid & 15;
        int ri = r / 3, rj = r % 3;
        float m = -3.402823466e38f;
#pragma unroll
        for (int rr2 = 0; rr2 < 2; ++rr2) {
            int rr = i + 16 * rr2;
            const float4* rowp = (const float4*)&img[(32 * ri + rr) * 96 + 32 * rj];
#pragma unroll
            for (int q = 0; q < 8; ++q) {
                float4 v = rowp[q];
                m = fmaxf(m, fmaxf(fmaxf(v.x, v.y), fmaxf(v.z, v.w)));
            }
        }
#pragma unroll
        for (int sh = 8; sh >= 1; sh >>= 1) m = fmaxf(m, __shfl_xor(m, sh));
        if (i == 0) p3[r] = m;
    }
    __syncthreads();
    if (tid < 30) {
        float v; int off;
        if (tid < 16) { v = p4[tid]; off = c * 16 + tid; }
        else if (tid < 25) { int q = tid - 16; v = p3[q]; off = 48 + c * 9 + q; }
        else if (tid < 29) {
            int q = tid - 25; int i2 = q >> 1, j2 = q & 1;
            v = fmaxf(fmaxf(p4[(2 * i2) * 4 + 2 * j2], p4[(2 * i2) * 4 + 2 * j2 + 1]),
                      fmaxf(p4[(2 * i2 + 1) * 4 + 2 * j2], p4[(2 * i2 + 1) * 4 + 2 * j2 + 1]));
            off = 75 + c * 4 + q;
        } else {
            float m = p4[0];
#pragma unroll
            for (int q = 1; q < 16; ++q) m = fmaxf(m, p4[q]);
            v = m; off = 87 + c;
        }
        out_pooled[(size_t)n * 90 + off] = v;
        ws_pooled[(size_t)n * 90 + off] = v;
    }
}

// ---------------- GEMM: Y(2048,4096) = relu(X(2048,90) @ W(4096,90)^T + b) ----------------
// grid (16 row-tiles, 32 col-tiles), 128x128 tile, 8x8 per-thread register tile, K padded to 96.
__global__ __launch_bounds__(256) void gemm90_kernel(const float* __restrict__ X,
                                                     const float* __restrict__ W,
                                                     const float* __restrict__ bias,
                                                     float* __restrict__ Y) {
    __shared__ __align__(16) float Xs[32][132];
    __shared__ __align__(16) float Ws[32][132];
    int tid = threadIdx.x;
    int R0 = blockIdx.x * 128, C0 = blockIdx.y * 128;
    int r0t = (tid >> 4) * 8, c0t = (tid & 15) * 8;
    float acc[8][8];
#pragma unroll
    for (int i = 0; i < 8; ++i)
#pragma unroll
        for (int j = 0; j < 8; ++j) acc[i][j] = 0.f;

    for (int k0 = 0; k0 < 96; k0 += 32) {
#pragma unroll
        for (int j = 0; j < 4; ++j) {            // X stage: garbage past k=90 is OK (W zeroed there)
            int idx = tid + 256 * j;
            int row = idx & 127, q = idx >> 7;
            int kg = k0 + 4 * q;
            const float2* p = (const float2*)&X[(size_t)(R0 + row) * 90 + kg];
            float2 a = p[0], b = p[1];
            Xs[4 * q + 0][row] = a.x; Xs[4 * q + 1][row] = a.y;
            Xs[4 * q + 2][row] = b.x; Xs[4 * q + 3][row] = b.y;
        }
#pragma unroll
        for (int j = 0; j < 4; ++j) {            // W stage: guarded, zero past k=90
            int idx = tid + 256 * j;
            int col = idx & 127, q = idx >> 7;
            int kg = k0 + 4 * q;
            float v0, v1, v2, v3;
            if (kg + 3 < 90) {
                const float2* p = (const float2*)&W[(size_t)(C0 + col) * 90 + kg];
                float2 a = p[0], b = p[1];
                v0 = a.x; v1 = a.y; v2 = b.x; v3 = b.y;
            } else {
                const float* p = &W[(size_t)(C0 + col) * 90];
                v0 = (kg + 0 < 90) ? p[kg + 0] : 0.f;
                v1 = (kg + 1 < 90) ? p[kg + 1] : 0.f;
                v2 = (kg + 2 < 90) ? p[kg + 2] : 0.f;
                v3 = (kg + 3 < 90) ? p[kg + 3] : 0.f;
            }
            Ws[4 * q + 0][col] = v0; Ws[4 * q + 1][col] = v1;
            Ws[4 * q + 2][col] = v2; Ws[4 * q + 3][col] = v3;
        }
        __syncthreads();
#pragma unroll 8
        for (int kk = 0; kk < 32; ++kk) {
            float4 xa = *(const float4*)&Xs[kk][r0t];
            float4 xb = *(const float4*)&Xs[kk][r0t + 4];
            float4 wa = *(const float4*)&Ws[kk][c0t];
            float4 wb = *(const float4*)&Ws[kk][c0t + 4];
            float xr[8] = {xa.x, xa.y, xa.z, xa.w, xb.x, xb.y, xb.z, xb.w};
            float wc[8] = {wa.x, wa.y, wa.z, wa.w, wb.x, wb.y, wb.z, wb.w};
#pragma unroll
            for (int i = 0; i < 8; ++i)
#pragma unroll
                for (int j = 0; j < 8; ++j) acc[i][j] += xr[i] * wc[j];
        }
        __syncthreads();
    }
    float4 ba = *(const float4*)&bias[C0 + c0t];
    float4 bb = *(const float4*)&bias[C0 + c0t + 4];
    float bs[8] = {ba.x, ba.y, ba.z, ba.w, bb.x, bb.y, bb.z, bb.w};
#pragma unroll
    for (int i = 0; i < 8; ++i) {
        float4 o0, o1;
        o0.x = fmaxf(acc[i][0] + bs[0], 0.f); o0.y = fmaxf(acc[i][1] + bs[1], 0.f);
        o0.z = fmaxf(acc[i][2] + bs[2], 0.f); o0.w = fmaxf(acc[i][3] + bs[3], 0.f);
        o1.x = fmaxf(acc[i][4] + bs[4], 0.f); o1.y = fmaxf(acc[i][5] + bs[5], 0.f);
        o1.z = fmaxf(acc[i][6] + bs[6], 0.f); o1.w = fmaxf(acc[i][7] + bs[7], 0.f);
        *(float4*)&Y[(size_t)(R0 + r0t + i) * 4096 + C0 + c0t] = o0;
        *(float4*)&Y[(size_t)(R0 + r0t + i) * 4096 + C0 + c0t + 4] = o1;
    }
}

// ---------------- GEMM: acc(2048,64) += X(2048,4096) @ W(64,4096)^T, K-split + atomics ----------------
__global__ __launch_bounds__(256) void gemmk_kernel(const float* __restrict__ X,
                                                    const float* __restrict__ W,
                                                    float* __restrict__ acc_out) {
    __shared__ __align__(16) float Xs[32][132];
    __shared__ __align__(16) float Ws[32][68];
    int tid = threadIdx.x;
    int R0 = blockIdx.x * 128;
    int K0 = blockIdx.y * 256;
    int r0t = (tid >> 4) * 8, c0t = (tid & 15) * 4;
    float acc[8][4];
#pragma unroll
    for (int i = 0; i < 8; ++i)
#pragma unroll
        for (int j = 0; j < 4; ++j) acc[i][j] = 0.f;

    for (int k0 = K0; k0 < K0 + 256; k0 += 32) {
#pragma unroll
        for (int j = 0; j < 4; ++j) {
            int idx = tid + 256 * j;
            int row = idx & 127, q = idx >> 7;
            float4 a = *(const float4*)&X[(size_t)(R0 + row) * 4096 + k0 + 4 * q];
            Xs[4 * q + 0][row] = a.x; Xs[4 * q + 1][row] = a.y;
            Xs[4 * q + 2][row] = a.z; Xs[4 * q + 3][row] = a.w;
        }
#pragma unroll
        for (int j = 0; j < 2; ++j) {
            int idx = tid + 256 * j;
            int col = idx & 63, q = idx >> 6;
            float4 a = *(const float4*)&W[(size_t)col * 4096 + k0 + 4 * q];
            Ws[4 * q + 0][col] = a.x; Ws[4 * q + 1][col] = a.y;
            Ws[4 * q + 2][col] = a.z; Ws[4 * q + 3][col] = a.w;
        }
        __syncthreads();
#pragma unroll 8
        for (int kk = 0; kk < 32; ++kk) {
            float4 xa = *(const float4*)&Xs[kk][r0t];
            float4 xb = *(const float4*)&Xs[kk][r0t + 4];
            float4 wa = *(const float4*)&Ws[kk][c0t];
            float xr[8] = {xa.x, xa.y, xa.z, xa.w, xb.x, xb.y, xb.z, xb.w};
            float wc[4] = {wa.x, wa.y, wa.z, wa.w};
#pragma unroll
            for (int i = 0; i < 8; ++i)
#pragma unroll
                for (int j = 0; j < 4; ++j) acc[i][j] += xr[i] * wc[j];
        }
        __syncthreads();
    }
#pragma unroll
    for (int i = 0; i < 8; ++i)
#pragma unroll
        for (int j = 0; j < 4; ++j)
            atomicAdd(&acc_out[(size_t)(R0 + r0t + i) * 64 + c0t + j], acc[i][j]);
}

// ---------------- X1 = relu(acc1 + fc7_b) @ wih1^T + bih1 + bhh1  -> (2048,256) ----------------
__global__ __launch_bounds__(256) void x1_kernel(const float* __restrict__ acc1,
                                                 const float* __restrict__ fc7_b,
                                                 const float* __restrict__ wih1,
                                                 const float* __restrict__ bih1,
                                                 const float* __restrict__ bhh1,
                                                 float* __restrict__ X1) {
    __shared__ __align__(16) float xr[8][64];
    int tid = threadIdx.x;
    int R0 = blockIdx.x * 8;
#pragma unroll
    for (int j = 0; j < 2; ++j) {
        int idx = tid + 256 * j;
        int r = idx >> 6, k = idx & 63;
        xr[r][k] = fmaxf(acc1[(size_t)(R0 + r) * 64 + k] + fc7_b[k], 0.f);
    }
    __syncthreads();
    int u = tid;
    float w[64];
#pragma unroll
    for (int q = 0; q < 16; ++q) {
        float4 a = *(const float4*)&wih1[(size_t)u * 64 + 4 * q];
        w[4 * q] = a.x; w[4 * q + 1] = a.y; w[4 * q + 2] = a.z; w[4 * q + 3] = a.w;
    }
    float bias = bih1[u] + bhh1[u];
    for (int r = 0; r < 8; ++r) {
        float g = bias;
#pragma unroll
        for (int k = 0; k < 64; ++k) g += w[k] * xr[r][k];
        X1[(size_t)(R0 + r) * 256 + u] = g;
    }
}

// ---------------- sequential 2-layer LSTM over 256 steps; one block per batch ----------------
__global__ __launch_bounds__(256) void seq_kernel(const float* __restrict__ X1,
                                                  const float* __restrict__ whh1,
                                                  const float* __restrict__ wih2,
                                                  const float* __restrict__ whh2,
                                                  const float* __restrict__ bih2,
                                                  const float* __restrict__ bhh2,
                                                  float* __restrict__ h1_all, float* __restrict__ c1_all,
                                                  float* __restrict__ h2_all, float* __restrict__ c2_all) {
    __shared__ __align__(16) float h1s[64];
    __shared__ __align__(16) float h2s[32];
    __shared__ float g1[256];
    __shared__ float p2[256];
    int u = threadIdx.x;
    size_t n0 = (size_t)blockIdx.x * 256;
    float w1[64];
#pragma unroll
    for (int q = 0; q < 16; ++q) {
        float4 a = *(const float4*)&whh1[(size_t)u * 64 + 4 * q];
        w1[4 * q] = a.x; w1[4 * q + 1] = a.y; w1[4 * q + 2] = a.z; w1[4 * q + 3] = a.w;
    }
    float w2[64]; float b2 = 0.f;
    if (u < 128) {
#pragma unroll
        for (int q = 0; q < 16; ++q) {
            float4 a = *(const float4*)&wih2[(size_t)u * 64 + 4 * q];
            w2[4 * q] = a.x; w2[4 * q + 1] = a.y; w2[4 * q + 2] = a.z; w2[4 * q + 3] = a.w;
        }
        b2 = bih2[u] + bhh2[u];
    } else {
#pragma unroll
        for (int q = 0; q < 8; ++q) {
            float4 a = *(const float4*)&whh2[(size_t)(u - 128) * 32 + 4 * q];
            w2[4 * q] = a.x; w2[4 * q + 1] = a.y; w2[4 * q + 2] = a.z; w2[4 * q + 3] = a.w;
        }
    }
    float c1 = 0.f, c2 = 0.f;
    if (u < 64) h1s[u] = 0.f;
    if (u < 32) h2s[u] = 0.f;
    __syncthreads();
    float x1next = X1[n0 * 256 + u];
    for (int t = 0; t < 256; ++t) {
        float g = x1next;
        if (t < 255) x1next = X1[(n0 + t + 1) * 256 + u];
#pragma unroll
        for (int q = 0; q < 16; ++q) {
            float4 h4 = *(const float4*)&h1s[4 * q];
            g += w1[4 * q] * h4.x + w1[4 * q + 1] * h4.y + w1[4 * q + 2] * h4.z + w1[4 * q + 3] * h4.w;
        }
        g1[u] = g;
        __syncthreads();
        if (u < 64) {
            float gi = g1[u], gf = g1[64 + u], gg = g1[128 + u], go = g1[192 + u];
            c1 = sigf(gf) * c1 + sigf(gi) * tanhf(gg);
            float h1n = sigf(go) * tanhf(c1);
            h1s[u] = h1n;
            h1_all[(n0 + t) * 64 + u] = h1n;
            c1_all[(n0 + t) * 64 + u] = c1;
        }
        __syncthreads();
        float p;
        if (u < 128) {
            p = b2;
#pragma unroll
            for (int q = 0; q < 16; ++q) {
                float4 h4 = *(const float4*)&h1s[4 * q];
                p += w2[4 * q] * h4.x + w2[4 * q + 1] * h4.y + w2[4 * q + 2] * h4.z + w2[4 * q + 3] * h4.w;
            }
        } else {
            p = 0.f;
#pragma unroll
            for (int q = 0; q < 8; ++q) {
                float4 h4 = *(const float4*)&h2s[4 * q];
                p += w2[4 * q] * h4.x + w2[4 * q + 1] * h4.y + w2[4 * q + 2] * h4.z + w2[4 * q + 3] * h4.w;
            }
        }
        p2[u] = p;
        __syncthreads();
        if (u < 32) {
            float gi = p2[u] + p2[128 + u];
            float gf = p2[32 + u] + p2[160 + u];
            float gg = p2[64 + u] + p2[192 + u];
            float go = p2[96 + u] + p2[224 + u];
            c2 = sigf(gf) * c2 + sigf(gi) * tanhf(gg);
            float h2n = sigf(go) * tanhf(c2);
            h2s[u] = h2n;
            h2_all[(n0 + t) * 32 + u] = h2n;
            c2_all[(n0 + t) * 32 + u] = c2;
        }
        __syncthreads();
    }
}

// ---------------- fpool + progress (parallel over all 2048 rows) ----------------
__global__ __launch_bounds__(256) void fpool_kernel(const float* __restrict__ h2_all,
                                                    const float* __restrict__ fw,
                                                    const float* __restrict__ fb,
                                                    const float* __restrict__ fc8_w,
                                                    const float* __restrict__ fc8_b,
                                                    float* __restrict__ fpool_ws,
                                                    float* __restrict__ out_fpooled,
                                                    float* __restrict__ out_progress) {
    __shared__ __align__(16) float h2t[16][32];
    __shared__ float fwl[2880];
    int tid = threadIdx.x;
    int R0 = blockIdx.x * 16;
#pragma unroll
    for (int j = 0; j < 2; ++j) {
        int idx = tid + 256 * j;
        int r = idx >> 5, k = idx & 31;
        h2t[r][k] = h2_all[(size_t)(R0 + r) * 32 + k];
    }
    for (int idx = tid; idx < 2880; idx += 256) fwl[idx] = fw[idx];
    __syncthreads();
    for (int j = 0; j < 6; ++j) {
        int idx = tid + 256 * j;
        if (idx < 1440) {
            int r = idx / 90, cc = idx % 90;
            float g = fb[cc];
#pragma unroll
            for (int k = 0; k < 32; ++k) g += h2t[r][k] * fwl[cc * 32 + k];
            fpool_ws[(size_t)(R0 + r) * 90 + cc] = g;
            out_fpooled[(size_t)(R0 + r) * 90 + cc] = g;
        }
    }
    if (tid < 16) {
        float g = fc8_b[0];
#pragma unroll
        for (int k = 0; k < 32; ++k) g += h2t[tid][k] * fc8_w[k];
        out_progress[R0 + tid] = sigf(g);
    }
}

// ---------------- forecast LSTM cells + fprogress (parallel over all 2048 rows) ----------------
__global__ __launch_bounds__(256) void fh_kernel(const float* __restrict__ acc2,
                                                 const float* __restrict__ fc7_b,
                                                 const float* __restrict__ h1_all,
                                                 const float* __restrict__ c1_all,
                                                 const float* __restrict__ h2_all,
                                                 const float* __restrict__ c2_all,
                                                 const float* __restrict__ wih1,
                                                 const float* __restrict__ whh1,
                                                 const float* __restrict__ bih1,
                                                 const float* __restrict__ bhh1,
                                                 const float* __restrict__ wih2,
                                                 const float* __restrict__ whh2,
                                                 const float* __restrict__ bih2,
                                                 const float* __restrict__ bhh2,
                                                 const float* __restrict__ fc8_w,
                                                 const float* __restrict__ fc8_b,
                                                 float* __restrict__ out_fprog) {
    __shared__ __align__(16) float xcat[8][128];   // [fe2 | h1]
    __shared__ float g1f[8][256];
    __shared__ __align__(16) float x2c[8][96];     // [fh1 | h2]
    __shared__ float g2f[8][128];
    __shared__ __align__(16) float fh2s[8][32];
    int tid = threadIdx.x;
    int R0 = blockIdx.x * 8;
#pragma unroll
    for (int j = 0; j < 4; ++j) {
        int idx = tid + 256 * j;
        int r = idx >> 7, k = idx & 127;
        float v;
        if (k < 64) v = fmaxf(acc2[(size_t)(R0 + r) * 64 + k] + fc7_b[k], 0.f);
        else v = h1_all[(size_t)(R0 + r) * 64 + (k - 64)];
        xcat[r][k] = v;
    }
    {
        int r = tid >> 5, k = tid & 31;
        x2c[r][64 + k] = h2_all[(size_t)(R0 + r) * 32 + k];
    }
    __syncthreads();
    {   // gates1f: 256 units, thread per unit, 8 rows
        int u = tid;
        float wa[64], wb[64];
#pragma unroll
        for (int q = 0; q < 16; ++q) {
            float4 a = *(const float4*)&wih1[(size_t)u * 64 + 4 * q];
            wa[4 * q] = a.x; wa[4 * q + 1] = a.y; wa[4 * q + 2] = a.z; wa[4 * q + 3] = a.w;
            float4 b = *(const float4*)&whh1[(size_t)u * 64 + 4 * q];
            wb[4 * q] = b.x; wb[4 * q + 1] = b.y; wb[4 * q + 2] = b.z; wb[4 * q + 3] = b.w;
        }
        float bias = bih1[u] + bhh1[u];
        for (int r = 0; r < 8; ++r) {
            float g = bias;
#pragma unroll
            for (int k = 0; k < 64; ++k) g += wa[k] * xcat[r][k];
#pragma unroll
            for (int k = 0; k < 64; ++k) g += wb[k] * xcat[r][64 + k];
            g1f[r][u] = g;
        }
    }
    __syncthreads();
#pragma unroll
    for (int j = 0; j < 2; ++j) {   // fh1 elementwise: 512 tasks
        int idx = tid + 256 * j;
        int r = idx >> 6, h = idx & 63;
        float gi = g1f[r][h], gf = g1f[r][64 + h], gg = g1f[r][128 + h], go = g1f[r][192 + h];
        float c1v = c1_all[(size_t)(R0 + r) * 64 + h];
        float c = sigf(gf) * c1v + sigf(gi) * tanhf(gg);
        x2c[r][h] = sigf(go) * tanhf(c);
    }
    __syncthreads();
    {   // gates2f: 128 units x 8 rows
        int u = tid & 127;
        int rb = (tid >> 7) * 4;
        float wa[64], wb2[32];
#pragma unroll
        for (int q = 0; q < 16; ++q) {
            float4 a = *(const float4*)&wih2[(size_t)u * 64 + 4 * q];
            wa[4 * q] = a.x; wa[4 * q + 1] = a.y; wa[4 * q + 2] = a.z; wa[4 * q + 3] = a.w;
        }
#pragma unroll
        for (int q = 0; q < 8; ++q) {
            float4 b = *(const float4*)&whh2[(size_t)u * 32 + 4 * q];
            wb2[4 * q] = b.x; wb2[4 * q + 1] = b.y; wb2[4 * q + 2] = b.z; wb2[4 * q + 3] = b.w;
        }
        float bias = bih2[u] + bhh2[u];
        for (int r = rb; r < rb + 4; ++r) {
            float g = bias;
#pragma unroll
            for (int k = 0; k < 64; ++k) g += wa[k] * x2c[r][k];
#pragma unroll
            for (int k = 0; k < 32; ++k) g += wb2[k] * x2c[r][64 + k];
            g2f[r][u] = g;
        }
    }
    __syncthreads();
    {   // fh2 elementwise: 256 tasks
        int r = tid >> 5, v = tid & 31;
        float gi = g2f[r][v], gf = g2f[r][32 + v], gg = g2f[r][64 + v], go = g2f[r][96 + v];
        float c2v = c2_all[(size_t)(R0 + r) * 32 + v];
        float c = sigf(gf) * c2v + sigf(gi) * tanhf(gg);
        fh2s[r][v] = sigf(go) * tanhf(c);
    }
    __syncthreads();
    if (tid < 8) {
        float g = fc8_b[0];
#pragma unroll
        for (int k = 0; k < 32; ++k) g += fh2s[tid][k] * fc8_w[k];
        out_fprog[R0 + tid] = sigf(g);
    }
}

// ---------------- launch ----------------
extern "C" void kernel_launch(void* const* d_in, const int* in_sizes, int n_in,
                              void* d_out, int out_size, void* d_ws, size_t ws_size,
                              hipStream_t stream) {
    (void)in_sizes; (void)n_in; (void)out_size; (void)ws_size;
    const float* frames   = (const float*)d_in[0];
    const float* spp_fc_w = (const float*)d_in[1];
    const float* spp_fc_b = (const float*)d_in[2];
    const float* fc7_w    = (const float*)d_in[3];
    const float* fc7_b    = (const float*)d_in[4];
    const float* l1_wih   = (const float*)d_in[5];
    const float* l1_whh   = (const float*)d_in[6];
    const float* l1_bih   = (const float*)d_in[7];
    const float* l1_bhh   = (const float*)d_in[8];
    const float* l2_wih   = (const float*)d_in[9];
    const float* l2_whh   = (const float*)d_in[10];
    const float* l2_bih   = (const float*)d_in[11];
    const float* l2_bhh   = (const float*)d_in[12];
    const float* fo_w     = (const float*)d_in[13];
    const float* fo_b     = (const float*)d_in[14];
    const float* fc8_w    = (const float*)d_in[15];
    const float* fc8_b    = (const float*)d_in[16];
    float* out = (float*)d_out;
    float* ws  = (float*)d_ws;

    float* pooled = ws + OFF_POOLED;
    float* emb1   = ws + OFF_EMB1;
    float* acc1   = ws + OFF_ACC1;
    float* acc2   = ws + OFF_ACC2;
    float* X1     = ws + OFF_X1;
    float* fpool  = ws + OFF_FPOOL;
    float* h1a    = ws + OFF_H1;
    float* c1a    = ws + OFF_C1;
    float* h2a    = ws + OFF_H2;
    float* c2a    = ws + OFF_C2;

    float* out_prog    = out;
    float* out_fprog   = out + 2048;
    float* out_pooled  = out + 4096;
    float* out_fpooled = out + 188416;

    hipMemsetAsync(acc1, 0, (size_t)262144 * sizeof(float), stream);  // acc1+acc2 contiguous
    spp_kernel<<<6144, 256, 0, stream>>>(frames, out_pooled, pooled);
    gemm90_kernel<<<dim3(16, 32), 256, 0, stream>>>(pooled, spp_fc_w, spp_fc_b, emb1);
    gemmk_kernel<<<dim3(16, 16), 256, 0, stream>>>(emb1, fc7_w, acc1);
    x1_kernel<<<256, 256, 0, stream>>>(acc1, fc7_b, l1_wih, l1_bih, l1_bhh, X1);
    seq_kernel<<<8, 256, 0, stream>>>(X1, l1_whh, l2_wih, l2_whh, l2_bih, l2_bhh, h1a, c1a, h2a, c2a);
    fpool_kernel<<<128, 256, 0, stream>>>(h2a, fo_w, fo_b, fc8_w, fc8_b, fpool, out_fpooled, out_prog);
    gemm90_kernel<<<dim3(16, 32), 256, 0, stream>>>(fpool, spp_fc_w, spp_fc_b, emb1);
    gemmk_kernel<<<dim3(16, 16), 256, 0, stream>>>(emb1, fc7_w, acc2);
    fh_kernel<<<256, 256, 0, stream>>>(acc2, fc7_b, h1a, c1a, h2a, c2a,
                                       l1_wih, l1_whh, l1_bih, l1_bhh,
                                       l2_wih, l2_whh, l2_bih, l2_bhh,
                                       fc8_w, fc8_b, out_fprog);
}

// Round 2
// 944.782 us; speedup vs baseline: 1.0404x; 1.0404x over previous
//
#include <hip/hip_runtime.h>
#include <math.h>

// ---------------- ws layout (floats) ----------------
static const size_t OFF_POOLED = 0;                     // 2048*90
static const size_t OFF_EMB1   = 184320;                // 2048*4096 (reused for fe1)
static const size_t OFF_ACC1   = OFF_EMB1 + 8388608;    // 2048*64
static const size_t OFF_ACC2   = OFF_ACC1 + 131072;     // 2048*64
static const size_t OFF_X1     = OFF_ACC2 + 131072;     // 2048*256
static const size_t OFF_FPOOL  = OFF_X1 + 524288;       // 2048*90
static const size_t OFF_H1     = OFF_FPOOL + 184320;    // 2048*64
static const size_t OFF_C1     = OFF_H1 + 131072;       // 2048*64
static const size_t OFF_H2     = OFF_C1 + 131072;       // 2048*32
static const size_t OFF_C2     = OFF_H2 + 65536;        // 2048*32
// total = 9,936,896 floats ≈ 39.75 MB

// fast activations: threshold is 0.104, we're at 1e-3 — plenty of headroom.
__device__ __forceinline__ float fsig(float x) {
    return __builtin_amdgcn_rcpf(1.0f + __expf(-x));
}
__device__ __forceinline__ float ftanh(float x) {
    // 1 - 2/(e^{2x}+1); saturates correctly at +/-inf
    return 1.0f - 2.0f * __builtin_amdgcn_rcpf(__expf(2.0f * x) + 1.0f);
}

// ---------------- SPP: adaptive max pool levels 4,3,2,1 ----------------
__global__ __launch_bounds__(256) void spp_kernel(const float* __restrict__ frames,
                                                  float* __restrict__ out_pooled,
                                                  float* __restrict__ ws_pooled) {
    __shared__ __align__(16) float img[9216];
    __shared__ float p4[16], p3[9];
    int blk = blockIdx.x;          // n*3 + c
    int n = blk / 3, c = blk % 3;
    const float* src = frames + (size_t)blk * 9216;
    int tid = threadIdx.x;
    const float4* s4 = (const float4*)src;
    float4* i4 = (float4*)img;
#pragma unroll
    for (int j = 0; j < 9; ++j) i4[tid + 256 * j] = s4[tid + 256 * j];
    __syncthreads();
    // level 4: 16 regions of 24x24, 16 threads each
    {
        int r = tid >> 4, i = tid & 15;
        int ri = r >> 2, rj = r & 3;
        float m = -3.402823466e38f;
        for (int rr = i; rr < 24; rr += 16) {
            const float4* rowp = (const float4*)&img[(24 * ri + rr) * 96 + 24 * rj];
#pragma unroll
            for (int q = 0; q < 6; ++q) {
                float4 v = rowp[q];
                m = fmaxf(m, fmaxf(fmaxf(v.x, v.y), fmaxf(v.z, v.w)));
            }
        }
#pragma unroll
        for (int sh = 8; sh >= 1; sh >>= 1) m = fmaxf(m, __shfl_xor(m, sh));
        if (i == 0) p4[r] = m;
    }
    // level 3: 9 regions of 32x32, 16 threads each
    if (tid < 144) {
        int r = tid >> 4, i = tid & 15;
        int ri = r / 3, rj = r % 3;
        float m = -3.402823466e38f;
#pragma unroll
        for (int rr2 = 0; rr2 < 2; ++rr2) {
            int rr = i + 16 * rr2;
            const float4* rowp = (const float4*)&img[(32 * ri + rr) * 96 + 32 * rj];
#pragma unroll
            for (int q = 0; q < 8; ++q) {
                float4 v = rowp[q];
                m = fmaxf(m, fmaxf(fmaxf(v.x, v.y), fmaxf(v.z, v.w)));
            }
        }
#pragma unroll
        for (int sh = 8; sh >= 1; sh >>= 1) m = fmaxf(m, __shfl_xor(m, sh));
        if (i == 0) p3[r] = m;
    }
    __syncthreads();
    if (tid < 30) {
        float v; int off;
        if (tid < 16) { v = p4[tid]; off = c * 16 + tid; }
        else if (tid < 25) { int q = tid - 16; v = p3[q]; off = 48 + c * 9 + q; }
        else if (tid < 29) {
            int q = tid - 25; int i2 = q >> 1, j2 = q & 1;
            v = fmaxf(fmaxf(p4[(2 * i2) * 4 + 2 * j2], p4[(2 * i2) * 4 + 2 * j2 + 1]),
                      fmaxf(p4[(2 * i2 + 1) * 4 + 2 * j2], p4[(2 * i2 + 1) * 4 + 2 * j2 + 1]));
            off = 75 + c * 4 + q;
        } else {
            float m = p4[0];
#pragma unroll
            for (int q = 1; q < 16; ++q) m = fmaxf(m, p4[q]);
            v = m; off = 87 + c;
        }
        out_pooled[(size_t)n * 90 + off] = v;
        ws_pooled[(size_t)n * 90 + off] = v;
    }
}

// ---------------- GEMM: Y(2048,4096) = relu(X(2048,90) @ W(4096,90)^T + b) ----------------
__global__ __launch_bounds__(256) void gemm90_kernel(const float* __restrict__ X,
                                                     const float* __restrict__ W,
                                                     const float* __restrict__ bias,
                                                     float* __restrict__ Y) {
    __shared__ __align__(16) float Xs[32][132];
    __shared__ __align__(16) float Ws[32][132];
    int tid = threadIdx.x;
    int R0 = blockIdx.x * 128, C0 = blockIdx.y * 128;
    int r0t = (tid >> 4) * 8, c0t = (tid & 15) * 8;
    float acc[8][8];
#pragma unroll
    for (int i = 0; i < 8; ++i)
#pragma unroll
        for (int j = 0; j < 8; ++j) acc[i][j] = 0.f;

    for (int k0 = 0; k0 < 96; k0 += 32) {
#pragma unroll
        for (int j = 0; j < 4; ++j) {
            int idx = tid + 256 * j;
            int row = idx & 127, q = idx >> 7;
            int kg = k0 + 4 * q;
            const float2* p = (const float2*)&X[(size_t)(R0 + row) * 90 + kg];
            float2 a = p[0], b = p[1];
            Xs[4 * q + 0][row] = a.x; Xs[4 * q + 1][row] = a.y;
            Xs[4 * q + 2][row] = b.x; Xs[4 * q + 3][row] = b.y;
        }
#pragma unroll
        for (int j = 0; j < 4; ++j) {
            int idx = tid + 256 * j;
            int col = idx & 127, q = idx >> 7;
            int kg = k0 + 4 * q;
            float v0, v1, v2, v3;
            if (kg + 3 < 90) {
                const float2* p = (const float2*)&W[(size_t)(C0 + col) * 90 + kg];
                float2 a = p[0], b = p[1];
                v0 = a.x; v1 = a.y; v2 = b.x; v3 = b.y;
            } else {
                const float* p = &W[(size_t)(C0 + col) * 90];
                v0 = (kg + 0 < 90) ? p[kg + 0] : 0.f;
                v1 = (kg + 1 < 90) ? p[kg + 1] : 0.f;
                v2 = (kg + 2 < 90) ? p[kg + 2] : 0.f;
                v3 = (kg + 3 < 90) ? p[kg + 3] : 0.f;
            }
            Ws[4 * q + 0][col] = v0; Ws[4 * q + 1][col] = v1;
            Ws[4 * q + 2][col] = v2; Ws[4 * q + 3][col] = v3;
        }
        __syncthreads();
#pragma unroll 8
        for (int kk = 0; kk < 32; ++kk) {
            float4 xa = *(const float4*)&Xs[kk][r0t];
            float4 xb = *(const float4*)&Xs[kk][r0t + 4];
            float4 wa = *(const float4*)&Ws[kk][c0t];
            float4 wb = *(const float4*)&Ws[kk][c0t + 4];
            float xr[8] = {xa.x, xa.y, xa.z, xa.w, xb.x, xb.y, xb.z, xb.w};
            float wc[8] = {wa.x, wa.y, wa.z, wa.w, wb.x, wb.y, wb.z, wb.w};
#pragma unroll
            for (int i = 0; i < 8; ++i)
#pragma unroll
                for (int j = 0; j < 8; ++j) acc[i][j] += xr[i] * wc[j];
        }
        __syncthreads();
    }
    float4 ba = *(const float4*)&bias[C0 + c0t];
    float4 bb = *(const float4*)&bias[C0 + c0t + 4];
    float bs[8] = {ba.x, ba.y, ba.z, ba.w, bb.x, bb.y, bb.z, bb.w};
#pragma unroll
    for (int i = 0; i < 8; ++i) {
        float4 o0, o1;
        o0.x = fmaxf(acc[i][0] + bs[0], 0.f); o0.y = fmaxf(acc[i][1] + bs[1], 0.f);
        o0.z = fmaxf(acc[i][2] + bs[2], 0.f); o0.w = fmaxf(acc[i][3] + bs[3], 0.f);
        o1.x = fmaxf(acc[i][4] + bs[4], 0.f); o1.y = fmaxf(acc[i][5] + bs[5], 0.f);
        o1.z = fmaxf(acc[i][6] + bs[6], 0.f); o1.w = fmaxf(acc[i][7] + bs[7], 0.f);
        *(float4*)&Y[(size_t)(R0 + r0t + i) * 4096 + C0 + c0t] = o0;
        *(float4*)&Y[(size_t)(R0 + r0t + i) * 4096 + C0 + c0t + 4] = o1;
    }
}

// ---------------- GEMM: acc(2048,64) += X(2048,4096) @ W(64,4096)^T, K-split + atomics ----------------
__global__ __launch_bounds__(256) void gemmk_kernel(const float* __restrict__ X,
                                                    const float* __restrict__ W,
                                                    float* __restrict__ acc_out) {
    __shared__ __align__(16) float Xs[32][132];
    __shared__ __align__(16) float Ws[32][68];
    int tid = threadIdx.x;
    int R0 = blockIdx.x * 128;
    int K0 = blockIdx.y * 256;
    int r0t = (tid >> 4) * 8, c0t = (tid & 15) * 4;
    float acc[8][4];
#pragma unroll
    for (int i = 0; i < 8; ++i)
#pragma unroll
        for (int j = 0; j < 4; ++j) acc[i][j] = 0.f;

    for (int k0 = K0; k0 < K0 + 256; k0 += 32) {
#pragma unroll
        for (int j = 0; j < 4; ++j) {
            int idx = tid + 256 * j;
            int row = idx & 127, q = idx >> 7;
            float4 a = *(const float4*)&X[(size_t)(R0 + row) * 4096 + k0 + 4 * q];
            Xs[4 * q + 0][row] = a.x; Xs[4 * q + 1][row] = a.y;
            Xs[4 * q + 2][row] = a.z; Xs[4 * q + 3][row] = a.w;
        }
#pragma unroll
        for (int j = 0; j < 2; ++j) {
            int idx = tid + 256 * j;
            int col = idx & 63, q = idx >> 6;
            float4 a = *(const float4*)&W[(size_t)col * 4096 + k0 + 4 * q];
            Ws[4 * q + 0][col] = a.x; Ws[4 * q + 1][col] = a.y;
            Ws[4 * q + 2][col] = a.z; Ws[4 * q + 3][col] = a.w;
        }
        __syncthreads();
#pragma unroll 8
        for (int kk = 0; kk < 32; ++kk) {
            float4 xa = *(const float4*)&Xs[kk][r0t];
            float4 xb = *(const float4*)&Xs[kk][r0t + 4];
            float4 wa = *(const float4*)&Ws[kk][c0t];
            float xr[8] = {xa.x, xa.y, xa.z, xa.w, xb.x, xb.y, xb.z, xb.w};
            float wc[4] = {wa.x, wa.y, wa.z, wa.w};
#pragma unroll
            for (int i = 0; i < 8; ++i)
#pragma unroll
                for (int j = 0; j < 4; ++j) acc[i][j] += xr[i] * wc[j];
        }
        __syncthreads();
    }
#pragma unroll
    for (int i = 0; i < 8; ++i)
#pragma unroll
        for (int j = 0; j < 4; ++j)
            atomicAdd(&acc_out[(size_t)(R0 + r0t + i) * 64 + c0t + j], acc[i][j]);
}

// ---------------- X1 = relu(acc1 + fc7_b) @ wih1^T + bih1 + bhh1  -> (2048,256) ----------------
__global__ __launch_bounds__(256) void x1_kernel(const float* __restrict__ acc1,
                                                 const float* __restrict__ fc7_b,
                                                 const float* __restrict__ wih1,
                                                 const float* __restrict__ bih1,
                                                 const float* __restrict__ bhh1,
                                                 float* __restrict__ X1) {
    __shared__ __align__(16) float xr[8][64];
    int tid = threadIdx.x;
    int R0 = blockIdx.x * 8;
#pragma unroll
    for (int j = 0; j < 2; ++j) {
        int idx = tid + 256 * j;
        int r = idx >> 6, k = idx & 63;
        xr[r][k] = fmaxf(acc1[(size_t)(R0 + r) * 64 + k] + fc7_b[k], 0.f);
    }
    __syncthreads();
    int u = tid;
    float w[64];
#pragma unroll
    for (int q = 0; q < 16; ++q) {
        float4 a = *(const float4*)&wih1[(size_t)u * 64 + 4 * q];
        w[4 * q] = a.x; w[4 * q + 1] = a.y; w[4 * q + 2] = a.z; w[4 * q + 3] = a.w;
    }
    float bias = bih1[u] + bhh1[u];
    for (int r = 0; r < 8; ++r) {
        float g = bias;
#pragma unroll
        for (int k = 0; k < 64; ++k) g += w[k] * xr[r][k];
        X1[(size_t)(R0 + r) * 256 + u] = g;
    }
}

// ---------------- sequential 2-layer LSTM; one block (2 waves) per batch ----------------
// Lane ownership chosen so every LSTM unit's gate exchange is intra-wave (shuffles);
// only the h1/h2 cross-wave broadcast needs a barrier. h1s/h2s double-buffered by
// step parity => exactly ONE __syncthreads per step.
__global__ __launch_bounds__(128, 1) void seq_kernel(const float* __restrict__ X1,
                                                     const float* __restrict__ whh1,
                                                     const float* __restrict__ wih2,
                                                     const float* __restrict__ whh2,
                                                     const float* __restrict__ bih2,
                                                     const float* __restrict__ bhh2,
                                                     float* __restrict__ h1_all, float* __restrict__ c1_all,
                                                     float* __restrict__ h2_all, float* __restrict__ c2_all) {
    __shared__ __align__(16) float h1s[2][64];
    __shared__ __align__(16) float h2s[2][32];
    const int tid = threadIdx.x;       // 0..127
    const int wave = tid >> 6;         // 0 or 1
    const int lane = tid & 63;
    const size_t n0 = (size_t)blockIdx.x * 256;

    // L1: wave w, lane l<32 owns rows (i,f) of unit u1=w*32+l; lane l>=32 owns (g,o) of same u1.
    const int u1 = wave * 32 + (lane & 31);
    const int rA = (lane < 32) ? u1 : (128 + u1);
    const int rB = rA + 64;
    float w1a[64], w1b[64];
    {
        const float4* pa = (const float4*)(whh1 + (size_t)rA * 64);
        const float4* pb = (const float4*)(whh1 + (size_t)rB * 64);
#pragma unroll
        for (int q = 0; q < 16; ++q) {
            float4 a = pa[q], b = pb[q];
            w1a[4 * q] = a.x; w1a[4 * q + 1] = a.y; w1a[4 * q + 2] = a.z; w1a[4 * q + 3] = a.w;
            w1b[4 * q] = b.x; w1b[4 * q + 1] = b.y; w1b[4 * q + 2] = b.z; w1b[4 * q + 3] = b.w;
        }
    }
    // L2: lane l owns gate q=(l>>4) of unit u2=w*16+(l&15) -> row r2=q*32+u2.
    const int u2 = wave * 16 + (lane & 15);
    const int r2 = (lane >> 4) * 32 + u2;
    float w2a[64], w2b[32];
    {
        const float4* pa = (const float4*)(wih2 + (size_t)r2 * 64);
#pragma unroll
        for (int q = 0; q < 16; ++q) {
            float4 a = pa[q];
            w2a[4 * q] = a.x; w2a[4 * q + 1] = a.y; w2a[4 * q + 2] = a.z; w2a[4 * q + 3] = a.w;
        }
        const float4* pb = (const float4*)(whh2 + (size_t)r2 * 32);
#pragma unroll
        for (int q = 0; q < 8; ++q) {
            float4 b = pb[q];
            w2b[4 * q] = b.x; w2b[4 * q + 1] = b.y; w2b[4 * q + 2] = b.z; w2b[4 * q + 3] = b.w;
        }
    }
    const float b2 = bih2[r2] + bhh2[r2];

    float c1 = 0.f, c2 = 0.f;
    if (tid < 64) { h1s[0][tid] = 0.f; h1s[1][tid] = 0.f; }
    if (tid < 32) { h2s[0][tid] = 0.f; h2s[1][tid] = 0.f; }
    __syncthreads();

    float xa_n = X1[n0 * 256 + rA];
    float xb_n = X1[n0 * 256 + rB];
    for (int t = 0; t < 256; ++t) {
        const int cur = t & 1, prv = cur ^ 1;
        float ga = xa_n, gb = xb_n;
        if (t < 255) {
            xa_n = X1[(n0 + t + 1) * 256 + rA];
            xb_n = X1[(n0 + t + 1) * 256 + rB];
        }
        const float* h1p = h1s[prv];
#pragma unroll
        for (int q = 0; q < 16; ++q) {
            float4 h4 = *(const float4*)&h1p[4 * q];
            ga += w1a[4 * q] * h4.x + w1a[4 * q + 1] * h4.y + w1a[4 * q + 2] * h4.z + w1a[4 * q + 3] * h4.w;
            gb += w1b[4 * q] * h4.x + w1b[4 * q + 1] * h4.y + w1b[4 * q + 2] * h4.z + w1b[4 * q + 3] * h4.w;
        }
        // lanes<32 hold (i,f); fetch (g,o) from lane l|32 via shuffle (intra-wave, no barrier)
        float xg = __shfl(ga, (lane & 31) | 32);
        float xo = __shfl(gb, (lane & 31) | 32);
        if (lane < 32) {
            c1 = fsig(gb) * c1 + fsig(ga) * ftanh(xg);
            float h1n = fsig(xo) * ftanh(c1);
            h1s[cur][u1] = h1n;
            h1_all[(n0 + t) * 64 + u1] = h1n;
            c1_all[(n0 + t) * 64 + u1] = c1;
        }
        __syncthreads();   // h1(t) visible to both waves; the ONLY barrier in the step
        // L2 gate: p = b2 + wih2[r2,:]·h1(t) + whh2[r2,:]·h2(t-1); two accumulators
        float p0 = b2, p1 = 0.f;
        const float* h1c = h1s[cur];
#pragma unroll
        for (int q = 0; q < 8; ++q) {
            float4 a = *(const float4*)&h1c[8 * q];
            float4 b = *(const float4*)&h1c[8 * q + 4];
            p0 += w2a[8 * q] * a.x + w2a[8 * q + 1] * a.y + w2a[8 * q + 2] * a.z + w2a[8 * q + 3] * a.w;
            p1 += w2a[8 * q + 4] * b.x + w2a[8 * q + 5] * b.y + w2a[8 * q + 6] * b.z + w2a[8 * q + 7] * b.w;
        }
        const float* h2p = h2s[prv];
#pragma unroll
        for (int q = 0; q < 4; ++q) {
            float4 a = *(const float4*)&h2p[8 * q];
            float4 b = *(const float4*)&h2p[8 * q + 4];
            p0 += w2b[8 * q] * a.x + w2b[8 * q + 1] * a.y + w2b[8 * q + 2] * a.z + w2b[8 * q + 3] * a.w;
            p1 += w2b[8 * q + 4] * b.x + w2b[8 * q + 5] * b.y + w2b[8 * q + 6] * b.z + w2b[8 * q + 7] * b.w;
        }
        float p = p0 + p1;
        // gather i,f,g,o for unit u2 onto lanes<16 (intra-wave)
        float gi = __shfl(p, lane & 15);
        float gf = __shfl(p, (lane & 15) | 16);
        float gg = __shfl(p, (lane & 15) | 32);
        float go = __shfl(p, (lane & 15) | 48);
        if (lane < 16) {
            c2 = fsig(gf) * c2 + fsig(gi) * ftanh(gg);
            float h2n = fsig(go) * ftanh(c2);
            h2s[cur][u2] = h2n;
            h2_all[(n0 + t) * 32 + u2] = h2n;
            c2_all[(n0 + t) * 32 + u2] = c2;
        }
        // no end-of-step barrier needed: h2s[cur] is only read after the NEXT step's
        // barrier, and all LDS buffers are parity-disjoint between barriers.
    }
}

// ---------------- fpool + progress (parallel over all 2048 rows) ----------------
__global__ __launch_bounds__(256) void fpool_kernel(const float* __restrict__ h2_all,
                                                    const float* __restrict__ fw,
                                                    const float* __restrict__ fb,
                                                    const float* __restrict__ fc8_w,
                                                    const float* __restrict__ fc8_b,
                                                    float* __restrict__ fpool_ws,
                                                    float* __restrict__ out_fpooled,
                                                    float* __restrict__ out_progress) {
    __shared__ __align__(16) float h2t[16][32];
    __shared__ float fwl[2880];
    int tid = threadIdx.x;
    int R0 = blockIdx.x * 16;
#pragma unroll
    for (int j = 0; j < 2; ++j) {
        int idx = tid + 256 * j;
        int r = idx >> 5, k = idx & 31;
        h2t[r][k] = h2_all[(size_t)(R0 + r) * 32 + k];
    }
    for (int idx = tid; idx < 2880; idx += 256) fwl[idx] = fw[idx];
    __syncthreads();
    for (int j = 0; j < 6; ++j) {
        int idx = tid + 256 * j;
        if (idx < 1440) {
            int r = idx / 90, cc = idx % 90;
            float g = fb[cc];
#pragma unroll
            for (int k = 0; k < 32; ++k) g += h2t[r][k] * fwl[cc * 32 + k];
            fpool_ws[(size_t)(R0 + r) * 90 + cc] = g;
            out_fpooled[(size_t)(R0 + r) * 90 + cc] = g;
        }
    }
    if (tid < 16) {
        float g = fc8_b[0];
#pragma unroll
        for (int k = 0; k < 32; ++k) g += h2t[tid][k] * fc8_w[k];
        out_progress[R0 + tid] = fsig(g);
    }
}

// ---------------- forecast LSTM cells + fprogress (parallel over all 2048 rows) ----------------
__global__ __launch_bounds__(256) void fh_kernel(const float* __restrict__ acc2,
                                                 const float* __restrict__ fc7_b,
                                                 const float* __restrict__ h1_all,
                                                 const float* __restrict__ c1_all,
                                                 const float* __restrict__ h2_all,
                                                 const float* __restrict__ c2_all,
                                                 const float* __restrict__ wih1,
                                                 const float* __restrict__ whh1,
                                                 const float* __restrict__ bih1,
                                                 const float* __restrict__ bhh1,
                                                 const float* __restrict__ wih2,
                                                 const float* __restrict__ whh2,
                                                 const float* __restrict__ bih2,
                                                 const float* __restrict__ bhh2,
                                                 const float* __restrict__ fc8_w,
                                                 const float* __restrict__ fc8_b,
                                                 float* __restrict__ out_fprog) {
    __shared__ __align__(16) float xcat[8][128];   // [fe2 | h1]
    __shared__ float g1f[8][256];
    __shared__ __align__(16) float x2c[8][96];     // [fh1 | h2]
    __shared__ float g2f[8][128];
    __shared__ __align__(16) float fh2s[8][32];
    int tid = threadIdx.x;
    int R0 = blockIdx.x * 8;
#pragma unroll
    for (int j = 0; j < 4; ++j) {
        int idx = tid + 256 * j;
        int r = idx >> 7, k = idx & 127;
        float v;
        if (k < 64) v = fmaxf(acc2[(size_t)(R0 + r) * 64 + k] + fc7_b[k], 0.f);
        else v = h1_all[(size_t)(R0 + r) * 64 + (k - 64)];
        xcat[r][k] = v;
    }
    {
        int r = tid >> 5, k = tid & 31;
        x2c[r][64 + k] = h2_all[(size_t)(R0 + r) * 32 + k];
    }
    __syncthreads();
    {   // gates1f: 256 units, thread per unit, 8 rows
        int u = tid;
        float wa[64], wb[64];
#pragma unroll
        for (int q = 0; q < 16; ++q) {
            float4 a = *(const float4*)&wih1[(size_t)u * 64 + 4 * q];
            wa[4 * q] = a.x; wa[4 * q + 1] = a.y; wa[4 * q + 2] = a.z; wa[4 * q + 3] = a.w;
            float4 b = *(const float4*)&whh1[(size_t)u * 64 + 4 * q];
            wb[4 * q] = b.x; wb[4 * q + 1] = b.y; wb[4 * q + 2] = b.z; wb[4 * q + 3] = b.w;
        }
        float bias = bih1[u] + bhh1[u];
        for (int r = 0; r < 8; ++r) {
            float g = bias;
#pragma unroll
            for (int k = 0; k < 64; ++k) g += wa[k] * xcat[r][k];
#pragma unroll
            for (int k = 0; k < 64; ++k) g += wb[k] * xcat[r][64 + k];
            g1f[r][u] = g;
        }
    }
    __syncthreads();
#pragma unroll
    for (int j = 0; j < 2; ++j) {   // fh1 elementwise: 512 tasks
        int idx = tid + 256 * j;
        int r = idx >> 6, h = idx & 63;
        float gi = g1f[r][h], gf = g1f[r][64 + h], gg = g1f[r][128 + h], go = g1f[r][192 + h];
        float c1v = c1_all[(size_t)(R0 + r) * 64 + h];
        float c = fsig(gf) * c1v + fsig(gi) * ftanh(gg);
        x2c[r][h] = fsig(go) * ftanh(c);
    }
    __syncthreads();
    {   // gates2f: 128 units x 8 rows
        int u = tid & 127;
        int rb = (tid >> 7) * 4;
        float wa[64], wb2[32];
#pragma unroll
        for (int q = 0; q < 16; ++q) {
            float4 a = *(const float4*)&wih2[(size_t)u * 64 + 4 * q];
            wa[4 * q] = a.x; wa[4 * q + 1] = a.y; wa[4 * q + 2] = a.z; wa[4 * q + 3] = a.w;
        }
#pragma unroll
        for (int q = 0; q < 8; ++q) {
            float4 b = *(const float4*)&whh2[(size_t)u * 32 + 4 * q];
            wb2[4 * q] = b.x; wb2[4 * q + 1] = b.y; wb2[4 * q + 2] = b.z; wb2[4 * q + 3] = b.w;
        }
        float bias = bih2[u] + bhh2[u];
        for (int r = rb; r < rb + 4; ++r) {
            float g = bias;
#pragma unroll
            for (int k = 0; k < 64; ++k) g += wa[k] * x2c[r][k];
#pragma unroll
            for (int k = 0; k < 32; ++k) g += wb2[k] * x2c[r][64 + k];
            g2f[r][u] = g;
        }
    }
    __syncthreads();
    {   // fh2 elementwise: 256 tasks
        int r = tid >> 5, v = tid & 31;
        float gi = g2f[r][v], gf = g2f[r][32 + v], gg = g2f[r][64 + v], go = g2f[r][96 + v];
        float c2v = c2_all[(size_t)(R0 + r) * 32 + v];
        float c = fsig(gf) * c2v + fsig(gi) * ftanh(gg);
        fh2s[r][v] = fsig(go) * ftanh(c);
    }
    __syncthreads();
    if (tid < 8) {
        float g = fc8_b[0];
#pragma unroll
        for (int k = 0; k < 32; ++k) g += fh2s[tid][k] * fc8_w[k];
        out_fprog[R0 + tid] = fsig(g);
    }
}

// ---------------- launch ----------------
extern "C" void kernel_launch(void* const* d_in, const int* in_sizes, int n_in,
                              void* d_out, int out_size, void* d_ws, size_t ws_size,
                              hipStream_t stream) {
    (void)in_sizes; (void)n_in; (void)out_size; (void)ws_size;
    const float* frames   = (const float*)d_in[0];
    const float* spp_fc_w = (const float*)d_in[1];
    const float* spp_fc_b = (const float*)d_in[2];
    const float* fc7_w    = (const float*)d_in[3];
    const float* fc7_b    = (const float*)d_in[4];
    const float* l1_wih   = (const float*)d_in[5];
    const float* l1_whh   = (const float*)d_in[6];
    const float* l1_bih   = (const float*)d_in[7];
    const float* l1_bhh   = (const float*)d_in[8];
    const float* l2_wih   = (const float*)d_in[9];
    const float* l2_whh   = (const float*)d_in[10];
    const float* l2_bih   = (const float*)d_in[11];
    const float* l2_bhh   = (const float*)d_in[12];
    const float* fo_w     = (const float*)d_in[13];
    const float* fo_b     = (const float*)d_in[14];
    const float* fc8_w    = (const float*)d_in[15];
    const float* fc8_b    = (const float*)d_in[16];
    float* out = (float*)d_out;
    float* ws  = (float*)d_ws;

    float* pooled = ws + OFF_POOLED;
    float* emb1   = ws + OFF_EMB1;
    float* acc1   = ws + OFF_ACC1;
    float* acc2   = ws + OFF_ACC2;
    float* X1     = ws + OFF_X1;
    float* fpool  = ws + OFF_FPOOL;
    float* h1a    = ws + OFF_H1;
    float* c1a    = ws + OFF_C1;
    float* h2a    = ws + OFF_H2;
    float* c2a    = ws + OFF_C2;

    float* out_prog    = out;
    float* out_fprog   = out + 2048;
    float* out_pooled  = out + 4096;
    float* out_fpooled = out + 188416;

    hipMemsetAsync(acc1, 0, (size_t)262144 * sizeof(float), stream);  // acc1+acc2 contiguous
    spp_kernel<<<6144, 256, 0, stream>>>(frames, out_pooled, pooled);
    gemm90_kernel<<<dim3(16, 32), 256, 0, stream>>>(pooled, spp_fc_w, spp_fc_b, emb1);
    gemmk_kernel<<<dim3(16, 16), 256, 0, stream>>>(emb1, fc7_w, acc1);
    x1_kernel<<<256, 256, 0, stream>>>(acc1, fc7_b, l1_wih, l1_bih, l1_bhh, X1);
    seq_kernel<<<8, 128, 0, stream>>>(X1, l1_whh, l2_wih, l2_whh, l2_bih, l2_bhh, h1a, c1a, h2a, c2a);
    fpool_kernel<<<128, 256, 0, stream>>>(h2a, fo_w, fo_b, fc8_w, fc8_b, fpool, out_fpooled, out_prog);
    gemm90_kernel<<<dim3(16, 32), 256, 0, stream>>>(fpool, spp_fc_w, spp_fc_b, emb1);
    gemmk_kernel<<<dim3(16, 16), 256, 0, stream>>>(emb1, fc7_w, acc2);
    fh_kernel<<<256, 256, 0, stream>>>(acc2, fc7_b, h1a, c1a, h2a, c2a,
                                       l1_wih, l1_whh, l1_bih, l1_bhh,
                                       l2_wih, l2_whh, l2_bih, l2_bhh,
                                       fc8_w, fc8_b, out_fprog);
}

// Round 3
// 783.642 us; speedup vs baseline: 1.2543x; 1.2056x over previous
//
#include <hip/hip_runtime.h>
#include <math.h>

// ---------------- ws layout (floats) ----------------
static const size_t OFF_POOLED = 0;                     // 2048*90
static const size_t OFF_EMB1   = 184320;                // 2048*4096 (reused for fe1)
static const size_t OFF_ACC1   = OFF_EMB1 + 8388608;    // 2048*64
static const size_t OFF_ACC2   = OFF_ACC1 + 131072;     // 2048*64
static const size_t OFF_X1     = OFF_ACC2 + 131072;     // 2048*256
static const size_t OFF_FPOOL  = OFF_X1 + 524288;       // 2048*90
static const size_t OFF_H1     = OFF_FPOOL + 184320;    // 2048*64
static const size_t OFF_C1     = OFF_H1 + 131072;       // 2048*64
static const size_t OFF_H2     = OFF_C1 + 131072;       // 2048*32
static const size_t OFF_C2     = OFF_H2 + 65536;        // 2048*32

typedef _Float16 h2f_t __attribute__((ext_vector_type(2)));

__device__ __forceinline__ float fsig(float x) {
    return __builtin_amdgcn_rcpf(1.0f + __expf(-x));
}
__device__ __forceinline__ float ftanh(float x) {
    return 1.0f - 2.0f * __builtin_amdgcn_rcpf(__expf(2.0f * x) + 1.0f);
}

// f32 += f16x2 · f16x2 (f32 accumulate). v_dot2_f32_f16 on gfx950.
__device__ __forceinline__ float fdot2(h2f_t a, h2f_t b, float c) {
#if __has_builtin(__builtin_amdgcn_fdot2)
    return __builtin_amdgcn_fdot2(a, b, c, false);
#else
    return c + (float)a.x * (float)b.x + (float)a.y * (float)b.y;  // -> v_fma_mix
#endif
}
__device__ __forceinline__ h2f_t h2pack(float x, float y) {
    h2f_t r; r.x = (_Float16)x; r.y = (_Float16)y; return r;
}
__device__ __forceinline__ h2f_t h2bits(int v) {
    return __builtin_bit_cast(h2f_t, v);
}
// wave-local LDS fence: DS ops of one wave retire in order; this drains lgkm
// (LDS write visibility) WITHOUT touching vmcnt — global stores stay in flight.
__device__ __forceinline__ void lds_fence() {
    asm volatile("s_waitcnt lgkmcnt(0)" ::: "memory");
}

// ---------------- SPP: adaptive max pool levels 4,3,2,1 ----------------
// Conflict-fixed: region lanes read consecutive elements (e = i + 16k).
__global__ __launch_bounds__(256) void spp_kernel(const float* __restrict__ frames,
                                                  float* __restrict__ out_pooled,
                                                  float* __restrict__ ws_pooled) {
    __shared__ __align__(16) float img[9216];
    __shared__ float p4[16], p3[9];
    int blk = blockIdx.x;          // n*3 + c
    int n = blk / 3, c = blk % 3;
    const float* src = frames + (size_t)blk * 9216;
    int tid = threadIdx.x;
    const float4* s4 = (const float4*)src;
    float4* i4 = (float4*)img;
#pragma unroll
    for (int j = 0; j < 9; ++j) i4[tid + 256 * j] = s4[tid + 256 * j];
    __syncthreads();
    // level 4: 16 regions of 24x24; 16 lanes/region read consecutive elements
    {
        int r = tid >> 4, i = tid & 15;
        int ri = r >> 2, rj = r & 3;
        const float* base = &img[(24 * ri) * 96 + 24 * rj];
        float m = -3.402823466e38f;
#pragma unroll 6
        for (int k = 0; k < 36; ++k) {
            int e = i + 16 * k;          // 0..575
            int row = e / 24;
            int col = e - row * 24;
            m = fmaxf(m, base[row * 96 + col]);
        }
#pragma unroll
        for (int sh = 8; sh >= 1; sh >>= 1) m = fmaxf(m, __shfl_xor(m, sh));
        if (i == 0) p4[r] = m;
    }
    // level 3: 9 regions of 32x32; 16 lanes/region, consecutive elements
    if (tid < 144) {
        int r = tid >> 4, i = tid & 15;
        int ri = r / 3, rj = r % 3;
        const float* base = &img[(32 * ri) * 96 + 32 * rj];
        float m = -3.402823466e38f;
#pragma unroll 8
        for (int k = 0; k < 64; ++k) {
            int e = i + 16 * k;          // 0..1023
            int row = e >> 5, col = e & 31;
            m = fmaxf(m, base[row * 96 + col]);
        }
#pragma unroll
        for (int sh = 8; sh >= 1; sh >>= 1) m = fmaxf(m, __shfl_xor(m, sh));
        if (i == 0) p3[r] = m;
    }
    __syncthreads();
    if (tid < 30) {
        float v; int off;
        if (tid < 16) { v = p4[tid]; off = c * 16 + tid; }
        else if (tid < 25) { int q = tid - 16; v = p3[q]; off = 48 + c * 9 + q; }
        else if (tid < 29) {
            int q = tid - 25; int i2 = q >> 1, j2 = q & 1;
            v = fmaxf(fmaxf(p4[(2 * i2) * 4 + 2 * j2], p4[(2 * i2) * 4 + 2 * j2 + 1]),
                      fmaxf(p4[(2 * i2 + 1) * 4 + 2 * j2], p4[(2 * i2 + 1) * 4 + 2 * j2 + 1]));
            off = 75 + c * 4 + q;
        } else {
            float m = p4[0];
#pragma unroll
            for (int q = 1; q < 16; ++q) m = fmaxf(m, p4[q]);
            v = m; off = 87 + c;
        }
        out_pooled[(size_t)n * 90 + off] = v;
        ws_pooled[(size_t)n * 90 + off] = v;
    }
}

// ---------------- GEMM: Y(2048,4096) = relu(X(2048,90) @ W(4096,90)^T + b) ----------------
__global__ __launch_bounds__(256) void gemm90_kernel(const float* __restrict__ X,
                                                     const float* __restrict__ W,
                                                     const float* __restrict__ bias,
                                                     float* __restrict__ Y) {
    __shared__ __align__(16) float Xs[32][132];
    __shared__ __align__(16) float Ws[32][132];
    int tid = threadIdx.x;
    int R0 = blockIdx.x * 128, C0 = blockIdx.y * 128;
    int r0t = (tid >> 4) * 8, c0t = (tid & 15) * 8;
    float acc[8][8];
#pragma unroll
    for (int i = 0; i < 8; ++i)
#pragma unroll
        for (int j = 0; j < 8; ++j) acc[i][j] = 0.f;

    for (int k0 = 0; k0 < 96; k0 += 32) {
#pragma unroll
        for (int j = 0; j < 4; ++j) {
            int idx = tid + 256 * j;
            int row = idx & 127, q = idx >> 7;
            int kg = k0 + 4 * q;
            const float2* p = (const float2*)&X[(size_t)(R0 + row) * 90 + kg];
            float2 a = p[0], b = p[1];
            Xs[4 * q + 0][row] = a.x; Xs[4 * q + 1][row] = a.y;
            Xs[4 * q + 2][row] = b.x; Xs[4 * q + 3][row] = b.y;
        }
#pragma unroll
        for (int j = 0; j < 4; ++j) {
            int idx = tid + 256 * j;
            int col = idx & 127, q = idx >> 7;
            int kg = k0 + 4 * q;
            float v0, v1, v2, v3;
            if (kg + 3 < 90) {
                const float2* p = (const float2*)&W[(size_t)(C0 + col) * 90 + kg];
                float2 a = p[0], b = p[1];
                v0 = a.x; v1 = a.y; v2 = b.x; v3 = b.y;
            } else {
                const float* p = &W[(size_t)(C0 + col) * 90];
                v0 = (kg + 0 < 90) ? p[kg + 0] : 0.f;
                v1 = (kg + 1 < 90) ? p[kg + 1] : 0.f;
                v2 = (kg + 2 < 90) ? p[kg + 2] : 0.f;
                v3 = (kg + 3 < 90) ? p[kg + 3] : 0.f;
            }
            Ws[4 * q + 0][col] = v0; Ws[4 * q + 1][col] = v1;
            Ws[4 * q + 2][col] = v2; Ws[4 * q + 3][col] = v3;
        }
        __syncthreads();
#pragma unroll 8
        for (int kk = 0; kk < 32; ++kk) {
            float4 xa = *(const float4*)&Xs[kk][r0t];
            float4 xb = *(const float4*)&Xs[kk][r0t + 4];
            float4 wa = *(const float4*)&Ws[kk][c0t];
            float4 wb = *(const float4*)&Ws[kk][c0t + 4];
            float xr[8] = {xa.x, xa.y, xa.z, xa.w, xb.x, xb.y, xb.z, xb.w};
            float wc[8] = {wa.x, wa.y, wa.z, wa.w, wb.x, wb.y, wb.z, wb.w};
#pragma unroll
            for (int i = 0; i < 8; ++i)
#pragma unroll
                for (int j = 0; j < 8; ++j) acc[i][j] += xr[i] * wc[j];
        }
        __syncthreads();
    }
    float4 ba = *(const float4*)&bias[C0 + c0t];
    float4 bb = *(const float4*)&bias[C0 + c0t + 4];
    float bs[8] = {ba.x, ba.y, ba.z, ba.w, bb.x, bb.y, bb.z, bb.w};
#pragma unroll
    for (int i = 0; i < 8; ++i) {
        float4 o0, o1;
        o0.x = fmaxf(acc[i][0] + bs[0], 0.f); o0.y = fmaxf(acc[i][1] + bs[1], 0.f);
        o0.z = fmaxf(acc[i][2] + bs[2], 0.f); o0.w = fmaxf(acc[i][3] + bs[3], 0.f);
        o1.x = fmaxf(acc[i][4] + bs[4], 0.f); o1.y = fmaxf(acc[i][5] + bs[5], 0.f);
        o1.z = fmaxf(acc[i][6] + bs[6], 0.f); o1.w = fmaxf(acc[i][7] + bs[7], 0.f);
        *(float4*)&Y[(size_t)(R0 + r0t + i) * 4096 + C0 + c0t] = o0;
        *(float4*)&Y[(size_t)(R0 + r0t + i) * 4096 + C0 + c0t + 4] = o1;
    }
}

// ---------------- GEMM: acc(2048,64) += X(2048,4096) @ W(64,4096)^T, K-split + atomics ----------------
__global__ __launch_bounds__(256) void gemmk_kernel(const float* __restrict__ X,
                                                    const float* __restrict__ W,
                                                    float* __restrict__ acc_out) {
    __shared__ __align__(16) float Xs[32][132];
    __shared__ __align__(16) float Ws[32][68];
    int tid = threadIdx.x;
    int R0 = blockIdx.x * 128;
    int K0 = blockIdx.y * 256;
    int r0t = (tid >> 4) * 8, c0t = (tid & 15) * 4;
    float acc[8][4];
#pragma unroll
    for (int i = 0; i < 8; ++i)
#pragma unroll
        for (int j = 0; j < 4; ++j) acc[i][j] = 0.f;

    for (int k0 = K0; k0 < K0 + 256; k0 += 32) {
#pragma unroll
        for (int j = 0; j < 4; ++j) {
            int idx = tid + 256 * j;
            int row = idx & 127, q = idx >> 7;
            float4 a = *(const float4*)&X[(size_t)(R0 + row) * 4096 + k0 + 4 * q];
            Xs[4 * q + 0][row] = a.x; Xs[4 * q + 1][row] = a.y;
            Xs[4 * q + 2][row] = a.z; Xs[4 * q + 3][row] = a.w;
        }
#pragma unroll
        for (int j = 0; j < 2; ++j) {
            int idx = tid + 256 * j;
            int col = idx & 63, q = idx >> 6;
            float4 a = *(const float4*)&W[(size_t)col * 4096 + k0 + 4 * q];
            Ws[4 * q + 0][col] = a.x; Ws[4 * q + 1][col] = a.y;
            Ws[4 * q + 2][col] = a.z; Ws[4 * q + 3][col] = a.w;
        }
        __syncthreads();
#pragma unroll 8
        for (int kk = 0; kk < 32; ++kk) {
            float4 xa = *(const float4*)&Xs[kk][r0t];
            float4 xb = *(const float4*)&Xs[kk][r0t + 4];
            float4 wa = *(const float4*)&Ws[kk][c0t];
            float xr[8] = {xa.x, xa.y, xa.z, xa.w, xb.x, xb.y, xb.z, xb.w};
            float wc[4] = {wa.x, wa.y, wa.z, wa.w};
#pragma unroll
            for (int i = 0; i < 8; ++i)
#pragma unroll
                for (int j = 0; j < 4; ++j) acc[i][j] += xr[i] * wc[j];
        }
        __syncthreads();
    }
#pragma unroll
    for (int i = 0; i < 8; ++i)
#pragma unroll
        for (int j = 0; j < 4; ++j)
            atomicAdd(&acc_out[(size_t)(R0 + r0t + i) * 64 + c0t + j], acc[i][j]);
}

// ---------------- X1 = relu(acc1 + fc7_b) @ wih1^T + bih1 + bhh1  -> (2048,256) ----------------
__global__ __launch_bounds__(256) void x1_kernel(const float* __restrict__ acc1,
                                                 const float* __restrict__ fc7_b,
                                                 const float* __restrict__ wih1,
                                                 const float* __restrict__ bih1,
                                                 const float* __restrict__ bhh1,
                                                 float* __restrict__ X1) {
    __shared__ __align__(16) float xr[8][64];
    int tid = threadIdx.x;
    int R0 = blockIdx.x * 8;
#pragma unroll
    for (int j = 0; j < 2; ++j) {
        int idx = tid + 256 * j;
        int r = idx >> 6, k = idx & 63;
        xr[r][k] = fmaxf(acc1[(size_t)(R0 + r) * 64 + k] + fc7_b[k], 0.f);
    }
    __syncthreads();
    int u = tid;
    float w[64];
#pragma unroll
    for (int q = 0; q < 16; ++q) {
        float4 a = *(const float4*)&wih1[(size_t)u * 64 + 4 * q];
        w[4 * q] = a.x; w[4 * q + 1] = a.y; w[4 * q + 2] = a.z; w[4 * q + 3] = a.w;
    }
    float bias = bih1[u] + bhh1[u];
    for (int r = 0; r < 8; ++r) {
        float g = bias;
#pragma unroll
        for (int k = 0; k < 64; ++k) g += w[k] * xr[r][k];
        X1[(size_t)(R0 + r) * 256 + u] = g;
    }
}

// ---------------- sequential 2-layer LSTM; ONE WAVE per batch ----------------
// Lane l owns L1 unit l (all 4 gate rows in-lane: rows l,64+l,128+l,192+l) and
// L2 rows l & 64+l. Weights/h packed f16, v_dot2_f32_f16 (f32 accumulate).
// No s_barrier anywhere: cross-lane h goes through LDS relying on wave-in-order
// DS retirement + lgkmcnt fences. Global stores & X1 prefetch never drained.
__global__ __launch_bounds__(64, 1) void seq_kernel(const float* __restrict__ X1,
                                                    const float* __restrict__ whh1,
                                                    const float* __restrict__ wih2,
                                                    const float* __restrict__ whh2,
                                                    const float* __restrict__ bih2,
                                                    const float* __restrict__ bhh2,
                                                    float* __restrict__ h1_all, float* __restrict__ c1_all,
                                                    float* __restrict__ h2_all, float* __restrict__ c2_all) {
    __shared__ __align__(16) _Float16 h1h[2][64];
    __shared__ __align__(16) _Float16 h2h[2][32];
    const int l = threadIdx.x;          // 0..63
    const size_t n0 = (size_t)blockIdx.x * 256;

    // pack whh1 rows l, 64+l, 128+l, 192+l -> f16 pairs (i,f,g,o in-lane)
    h2f_t w1[4][32];
#pragma unroll
    for (int g = 0; g < 4; ++g) {
        const float* wr = whh1 + (size_t)(g * 64 + l) * 64;
#pragma unroll
        for (int q = 0; q < 32; ++q) w1[g][q] = h2pack(wr[2 * q], wr[2 * q + 1]);
    }
    // L2: rows l and 64+l of wih2 (128x64) and whh2 (128x32)
    h2f_t w2a[2][32], w2b[2][16];
#pragma unroll
    for (int g = 0; g < 2; ++g) {
        const float* wa = wih2 + (size_t)(g * 64 + l) * 64;
#pragma unroll
        for (int q = 0; q < 32; ++q) w2a[g][q] = h2pack(wa[2 * q], wa[2 * q + 1]);
        const float* wb = whh2 + (size_t)(g * 64 + l) * 32;
#pragma unroll
        for (int q = 0; q < 16; ++q) w2b[g][q] = h2pack(wb[2 * q], wb[2 * q + 1]);
    }
    const float b2a = bih2[l] + bhh2[l];
    const float b2b = bih2[64 + l] + bhh2[64 + l];

    float c1 = 0.f, c2 = 0.f;
    h1h[0][l] = (_Float16)0.f; h1h[1][l] = (_Float16)0.f;
    if (l < 32) { h2h[0][l] = (_Float16)0.f; h2h[1][l] = (_Float16)0.f; }
    lds_fence();

    const float* xp = X1 + n0 * 256;
    float x0n = xp[l], x1n = xp[64 + l], x2n = xp[128 + l], x3n = xp[192 + l];

    for (int t = 0; t < 256; ++t) {
        const int cur = t & 1, prv = cur ^ 1;
        float a0 = x0n, a1 = x1n, a2 = x2n, a3 = x3n;
        if (t < 255) {
            const float* xq = xp + (size_t)(t + 1) * 256;
            x0n = xq[l]; x1n = xq[64 + l]; x2n = xq[128 + l]; x3n = xq[192 + l];
        }
        // L1 dot: 4 gates x 64 via 128 dot2 (h1(t-1) broadcast from LDS)
        const int4* h1v = (const int4*)h1h[prv];
#pragma unroll
        for (int q = 0; q < 8; ++q) {
            int4 v = h1v[q];
            h2f_t hh0 = h2bits(v.x), hh1 = h2bits(v.y), hh2 = h2bits(v.z), hh3 = h2bits(v.w);
            a0 = fdot2(w1[0][4 * q], hh0, a0); a1 = fdot2(w1[1][4 * q], hh0, a1);
            a2 = fdot2(w1[2][4 * q], hh0, a2); a3 = fdot2(w1[3][4 * q], hh0, a3);
            a0 = fdot2(w1[0][4 * q + 1], hh1, a0); a1 = fdot2(w1[1][4 * q + 1], hh1, a1);
            a2 = fdot2(w1[2][4 * q + 1], hh1, a2); a3 = fdot2(w1[3][4 * q + 1], hh1, a3);
            a0 = fdot2(w1[0][4 * q + 2], hh2, a0); a1 = fdot2(w1[1][4 * q + 2], hh2, a1);
            a2 = fdot2(w1[2][4 * q + 2], hh2, a2); a3 = fdot2(w1[3][4 * q + 2], hh2, a3);
            a0 = fdot2(w1[0][4 * q + 3], hh3, a0); a1 = fdot2(w1[1][4 * q + 3], hh3, a1);
            a2 = fdot2(w1[2][4 * q + 3], hh3, a2); a3 = fdot2(w1[3][4 * q + 3], hh3, a3);
        }
        // L1 cell (fully in-lane)
        c1 = fsig(a1) * c1 + fsig(a0) * ftanh(a2);
        float h1n = fsig(a3) * ftanh(c1);
        h1_all[(n0 + t) * 64 + l] = h1n;   // fire-and-forget (never drained)
        c1_all[(n0 + t) * 64 + l] = c1;
        // L2 h2-part (independent of h1n — hides the h1 LDS round-trip)
        float pa = b2a, pb = b2b;
        const int4* h2v = (const int4*)h2h[prv];
#pragma unroll
        for (int q = 0; q < 4; ++q) {
            int4 v = h2v[q];
            h2f_t hh0 = h2bits(v.x), hh1 = h2bits(v.y), hh2 = h2bits(v.z), hh3 = h2bits(v.w);
            pa = fdot2(w2b[0][4 * q], hh0, pa); pb = fdot2(w2b[1][4 * q], hh0, pb);
            pa = fdot2(w2b[0][4 * q + 1], hh1, pa); pb = fdot2(w2b[1][4 * q + 1], hh1, pb);
            pa = fdot2(w2b[0][4 * q + 2], hh2, pa); pb = fdot2(w2b[1][4 * q + 2], hh2, pb);
            pa = fdot2(w2b[0][4 * q + 3], hh3, pa); pb = fdot2(w2b[1][4 * q + 3], hh3, pb);
        }
        // publish h1(t) to the wave
        h1h[cur][l] = (_Float16)h1n;
        lds_fence();
        // L2 h1-part
        const int4* h1c = (const int4*)h1h[cur];
#pragma unroll
        for (int q = 0; q < 8; ++q) {
            int4 v = h1c[q];
            h2f_t hh0 = h2bits(v.x), hh1 = h2bits(v.y), hh2 = h2bits(v.z), hh3 = h2bits(v.w);
            pa = fdot2(w2a[0][4 * q], hh0, pa); pb = fdot2(w2a[1][4 * q], hh0, pb);
            pa = fdot2(w2a[0][4 * q + 1], hh1, pa); pb = fdot2(w2a[1][4 * q + 1], hh1, pb);
            pa = fdot2(w2a[0][4 * q + 2], hh2, pa); pb = fdot2(w2a[1][4 * q + 2], hh2, pb);
            pa = fdot2(w2a[0][4 * q + 3], hh3, pa); pb = fdot2(w2a[1][4 * q + 3], hh3, pb);
        }
        // lane l<32: pa=i,pb=g of unit l; lane l+32 holds f,o of unit l
        float gf_ = __shfl(pa, (l & 31) + 32);
        float go_ = __shfl(pb, (l & 31) + 32);
        if (l < 32) {
            c2 = fsig(gf_) * c2 + fsig(pa) * ftanh(pb);
            float h2n = fsig(go_) * ftanh(c2);
            h2h[cur][l] = (_Float16)h2n;
            h2_all[(n0 + t) * 32 + l] = h2n;
            c2_all[(n0 + t) * 32 + l] = c2;
        }
        lds_fence();   // h2(t) retired before next step's read (wave-in-order + fence)
    }
}

// ---------------- fpool + progress (parallel over all 2048 rows) ----------------
__global__ __launch_bounds__(256) void fpool_kernel(const float* __restrict__ h2_all,
                                                    const float* __restrict__ fw,
                                                    const float* __restrict__ fb,
                                                    const float* __restrict__ fc8_w,
                                                    const float* __restrict__ fc8_b,
                                                    float* __restrict__ fpool_ws,
                                                    float* __restrict__ out_fpooled,
                                                    float* __restrict__ out_progress) {
    __shared__ __align__(16) float h2t[16][32];
    __shared__ float fwl[2880];
    int tid = threadIdx.x;
    int R0 = blockIdx.x * 16;
#pragma unroll
    for (int j = 0; j < 2; ++j) {
        int idx = tid + 256 * j;
        int r = idx >> 5, k = idx & 31;
        h2t[r][k] = h2_all[(size_t)(R0 + r) * 32 + k];
    }
    for (int idx = tid; idx < 2880; idx += 256) fwl[idx] = fw[idx];
    __syncthreads();
    for (int j = 0; j < 6; ++j) {
        int idx = tid + 256 * j;
        if (idx < 1440) {
            int r = idx / 90, cc = idx % 90;
            float g = fb[cc];
#pragma unroll
            for (int k = 0; k < 32; ++k) g += h2t[r][k] * fwl[cc * 32 + k];
            fpool_ws[(size_t)(R0 + r) * 90 + cc] = g;
            out_fpooled[(size_t)(R0 + r) * 90 + cc] = g;
        }
    }
    if (tid < 16) {
        float g = fc8_b[0];
#pragma unroll
        for (int k = 0; k < 32; ++k) g += h2t[tid][k] * fc8_w[k];
        out_progress[R0 + tid] = fsig(g);
    }
}

// ---------------- forecast LSTM cells + fprogress (parallel over all 2048 rows) ----------------
__global__ __launch_bounds__(256) void fh_kernel(const float* __restrict__ acc2,
                                                 const float* __restrict__ fc7_b,
                                                 const float* __restrict__ h1_all,
                                                 const float* __restrict__ c1_all,
                                                 const float* __restrict__ h2_all,
                                                 const float* __restrict__ c2_all,
                                                 const float* __restrict__ wih1,
                                                 const float* __restrict__ whh1,
                                                 const float* __restrict__ bih1,
                                                 const float* __restrict__ bhh1,
                                                 const float* __restrict__ wih2,
                                                 const float* __restrict__ whh2,
                                                 const float* __restrict__ bih2,
                                                 const float* __restrict__ bhh2,
                                                 const float* __restrict__ fc8_w,
                                                 const float* __restrict__ fc8_b,
                                                 float* __restrict__ out_fprog) {
    __shared__ __align__(16) float xcat[8][128];   // [fe2 | h1]
    __shared__ float g1f[8][256];
    __shared__ __align__(16) float x2c[8][96];     // [fh1 | h2]
    __shared__ float g2f[8][128];
    __shared__ __align__(16) float fh2s[8][32];
    int tid = threadIdx.x;
    int R0 = blockIdx.x * 8;
#pragma unroll
    for (int j = 0; j < 4; ++j) {
        int idx = tid + 256 * j;
        int r = idx >> 7, k = idx & 127;
        float v;
        if (k < 64) v = fmaxf(acc2[(size_t)(R0 + r) * 64 + k] + fc7_b[k], 0.f);
        else v = h1_all[(size_t)(R0 + r) * 64 + (k - 64)];
        xcat[r][k] = v;
    }
    {
        int r = tid >> 5, k = tid & 31;
        x2c[r][64 + k] = h2_all[(size_t)(R0 + r) * 32 + k];
    }
    __syncthreads();
    {   // gates1f: 256 units, thread per unit, 8 rows
        int u = tid;
        float wa[64], wb[64];
#pragma unroll
        for (int q = 0; q < 16; ++q) {
            float4 a = *(const float4*)&wih1[(size_t)u * 64 + 4 * q];
            wa[4 * q] = a.x; wa[4 * q + 1] = a.y; wa[4 * q + 2] = a.z; wa[4 * q + 3] = a.w;
            float4 b = *(const float4*)&whh1[(size_t)u * 64 + 4 * q];
            wb[4 * q] = b.x; wb[4 * q + 1] = b.y; wb[4 * q + 2] = b.z; wb[4 * q + 3] = b.w;
        }
        float bias = bih1[u] + bhh1[u];
        for (int r = 0; r < 8; ++r) {
            float g = bias;
#pragma unroll
            for (int k = 0; k < 64; ++k) g += wa[k] * xcat[r][k];
#pragma unroll
            for (int k = 0; k < 64; ++k) g += wb[k] * xcat[r][64 + k];
            g1f[r][u] = g;
        }
    }
    __syncthreads();
#pragma unroll
    for (int j = 0; j < 2; ++j) {   // fh1 elementwise: 512 tasks
        int idx = tid + 256 * j;
        int r = idx >> 6, h = idx & 63;
        float gi = g1f[r][h], gf = g1f[r][64 + h], gg = g1f[r][128 + h], go = g1f[r][192 + h];
        float c1v = c1_all[(size_t)(R0 + r) * 64 + h];
        float c = fsig(gf) * c1v + fsig(gi) * ftanh(gg);
        x2c[r][h] = fsig(go) * ftanh(c);
    }
    __syncthreads();
    {   // gates2f: 128 units x 8 rows
        int u = tid & 127;
        int rb = (tid >> 7) * 4;
        float wa[64], wb2[32];
#pragma unroll
        for (int q = 0; q < 16; ++q) {
            float4 a = *(const float4*)&wih2[(size_t)u * 64 + 4 * q];
            wa[4 * q] = a.x; wa[4 * q + 1] = a.y; wa[4 * q + 2] = a.z; wa[4 * q + 3] = a.w;
        }
#pragma unroll
        for (int q = 0; q < 8; ++q) {
            float4 b = *(const float4*)&whh2[(size_t)u * 32 + 4 * q];
            wb2[4 * q] = b.x; wb2[4 * q + 1] = b.y; wb2[4 * q + 2] = b.z; wb2[4 * q + 3] = b.w;
        }
        float bias = bih2[u] + bhh2[u];
        for (int r = rb; r < rb + 4; ++r) {
            float g = bias;
#pragma unroll
            for (int k = 0; k < 64; ++k) g += wa[k] * x2c[r][k];
#pragma unroll
            for (int k = 0; k < 32; ++k) g += wb2[k] * x2c[r][64 + k];
            g2f[r][u] = g;
        }
    }
    __syncthreads();
    {   // fh2 elementwise: 256 tasks
        int r = tid >> 5, v = tid & 31;
        float gi = g2f[r][v], gf = g2f[r][32 + v], gg = g2f[r][64 + v], go = g2f[r][96 + v];
        float c2v = c2_all[(size_t)(R0 + r) * 32 + v];
        float c = fsig(gf) * c2v + fsig(gi) * ftanh(gg);
        fh2s[r][v] = fsig(go) * ftanh(c);
    }
    __syncthreads();
    if (tid < 8) {
        float g = fc8_b[0];
#pragma unroll
        for (int k = 0; k < 32; ++k) g += fh2s[tid][k] * fc8_w[k];
        out_fprog[R0 + tid] = fsig(g);
    }
}

// ---------------- launch ----------------
extern "C" void kernel_launch(void* const* d_in, const int* in_sizes, int n_in,
                              void* d_out, int out_size, void* d_ws, size_t ws_size,
                              hipStream_t stream) {
    (void)in_sizes; (void)n_in; (void)out_size; (void)ws_size;
    const float* frames   = (const float*)d_in[0];
    const float* spp_fc_w = (const float*)d_in[1];
    const float* spp_fc_b = (const float*)d_in[2];
    const float* fc7_w    = (const float*)d_in[3];
    const float* fc7_b    = (const float*)d_in[4];
    const float* l1_wih   = (const float*)d_in[5];
    const float* l1_whh   = (const float*)d_in[6];
    const float* l1_bih   = (const float*)d_in[7];
    const float* l1_bhh   = (const float*)d_in[8];
    const float* l2_wih   = (const float*)d_in[9];
    const float* l2_whh   = (const float*)d_in[10];
    const float* l2_bih   = (const float*)d_in[11];
    const float* l2_bhh   = (const float*)d_in[12];
    const float* fo_w     = (const float*)d_in[13];
    const float* fo_b     = (const float*)d_in[14];
    const float* fc8_w    = (const float*)d_in[15];
    const float* fc8_b    = (const float*)d_in[16];
    float* out = (float*)d_out;
    float* ws  = (float*)d_ws;

    float* pooled = ws + OFF_POOLED;
    float* emb1   = ws + OFF_EMB1;
    float* acc1   = ws + OFF_ACC1;
    float* acc2   = ws + OFF_ACC2;
    float* X1     = ws + OFF_X1;
    float* fpool  = ws + OFF_FPOOL;
    float* h1a    = ws + OFF_H1;
    float* c1a    = ws + OFF_C1;
    float* h2a    = ws + OFF_H2;
    float* c2a    = ws + OFF_C2;

    float* out_prog    = out;
    float* out_fprog   = out + 2048;
    float* out_pooled  = out + 4096;
    float* out_fpooled = out + 188416;

    hipMemsetAsync(acc1, 0, (size_t)262144 * sizeof(float), stream);  // acc1+acc2 contiguous
    spp_kernel<<<6144, 256, 0, stream>>>(frames, out_pooled, pooled);
    gemm90_kernel<<<dim3(16, 32), 256, 0, stream>>>(pooled, spp_fc_w, spp_fc_b, emb1);
    gemmk_kernel<<<dim3(16, 16), 256, 0, stream>>>(emb1, fc7_w, acc1);
    x1_kernel<<<256, 256, 0, stream>>>(acc1, fc7_b, l1_wih, l1_bih, l1_bhh, X1);
    seq_kernel<<<8, 64, 0, stream>>>(X1, l1_whh, l2_wih, l2_whh, l2_bih, l2_bhh, h1a, c1a, h2a, c2a);
    fpool_kernel<<<128, 256, 0, stream>>>(h2a, fo_w, fo_b, fc8_w, fc8_b, fpool, out_fpooled, out_prog);
    gemm90_kernel<<<dim3(16, 32), 256, 0, stream>>>(fpool, spp_fc_w, spp_fc_b, emb1);
    gemmk_kernel<<<dim3(16, 16), 256, 0, stream>>>(emb1, fc7_w, acc2);
    fh_kernel<<<256, 256, 0, stream>>>(acc2, fc7_b, h1a, c1a, h2a, c2a,
                                       l1_wih, l1_whh, l1_bih, l1_bhh,
                                       l2_wih, l2_whh, l2_bih, l2_bhh,
                                       fc8_w, fc8_b, out_fprog);
}

// Round 4
// 765.920 us; speedup vs baseline: 1.2833x; 1.0231x over previous
//
#include <hip/hip_runtime.h>
#include <math.h>

// ---------------- ws layout (floats) ----------------
static const size_t OFF_POOLED = 0;                     // 2048*90
static const size_t OFF_EMB1   = 184320;                // 2048*4096 (reused for fe1)
static const size_t OFF_ACC1   = OFF_EMB1 + 8388608;    // 2048*64
static const size_t OFF_ACC2   = OFF_ACC1 + 131072;     // 2048*64
static const size_t OFF_X1     = OFF_ACC2 + 131072;     // 2048*256
static const size_t OFF_FPOOL  = OFF_X1 + 524288;       // 2048*90
static const size_t OFF_H1     = OFF_FPOOL + 184320;    // 2048*64
static const size_t OFF_C1     = OFF_H1 + 131072;       // 2048*64
static const size_t OFF_H2     = OFF_C1 + 131072;       // 2048*32
static const size_t OFF_C2     = OFF_H2 + 65536;        // 2048*32

typedef _Float16 h2f_t __attribute__((ext_vector_type(2)));

__device__ __forceinline__ float fsig(float x) {
    return __builtin_amdgcn_rcpf(1.0f + __expf(-x));
}
__device__ __forceinline__ float ftanh(float x) {
    return 1.0f - 2.0f * __builtin_amdgcn_rcpf(__expf(2.0f * x) + 1.0f);
}

// f32 += f16x2 · f16x2 (f32 accumulate). v_dot2_f32_f16 on gfx950.
__device__ __forceinline__ float fdot2(h2f_t a, h2f_t b, float c) {
#if __has_builtin(__builtin_amdgcn_fdot2)
    return __builtin_amdgcn_fdot2(a, b, c, false);
#else
    return c + (float)a.x * (float)b.x + (float)a.y * (float)b.y;
#endif
}
__device__ __forceinline__ h2f_t h2pack(float x, float y) {
    h2f_t r; r.x = (_Float16)x; r.y = (_Float16)y; return r;
}
__device__ __forceinline__ h2f_t h2bits(int v) {
    return __builtin_bit_cast(h2f_t, v);
}
// wave-local LDS fence: drains lgkm (LDS visibility) WITHOUT touching vmcnt —
// global stores / prefetch loads stay in flight.
__device__ __forceinline__ void lds_fence() {
    asm volatile("s_waitcnt lgkmcnt(0)" ::: "memory");
}

// ---------------- SPP: adaptive max pool levels 4,3,2,1 ----------------
__global__ __launch_bounds__(256) void spp_kernel(const float* __restrict__ frames,
                                                  float* __restrict__ out_pooled,
                                                  float* __restrict__ ws_pooled) {
    __shared__ __align__(16) float img[9216];
    __shared__ float p4[16], p3[9];
    int blk = blockIdx.x;          // n*3 + c
    int n = blk / 3, c = blk % 3;
    const float* src = frames + (size_t)blk * 9216;
    int tid = threadIdx.x;
    const float4* s4 = (const float4*)src;
    float4* i4 = (float4*)img;
#pragma unroll
    for (int j = 0; j < 9; ++j) i4[tid + 256 * j] = s4[tid + 256 * j];
    __syncthreads();
    // level 4: 16 regions of 24x24; 16 lanes/region read consecutive elements
    {
        int r = tid >> 4, i = tid & 15;
        int ri = r >> 2, rj = r & 3;
        const float* base = &img[(24 * ri) * 96 + 24 * rj];
        float m = -3.402823466e38f;
#pragma unroll 6
        for (int k = 0; k < 36; ++k) {
            int e = i + 16 * k;          // 0..575
            int row = e / 24;
            int col = e - row * 24;
            m = fmaxf(m, base[row * 96 + col]);
        }
#pragma unroll
        for (int sh = 8; sh >= 1; sh >>= 1) m = fmaxf(m, __shfl_xor(m, sh));
        if (i == 0) p4[r] = m;
    }
    // level 3: 9 regions of 32x32; 16 lanes/region, consecutive elements
    if (tid < 144) {
        int r = tid >> 4, i = tid & 15;
        int ri = r / 3, rj = r % 3;
        const float* base = &img[(32 * ri) * 96 + 32 * rj];
        float m = -3.402823466e38f;
#pragma unroll 8
        for (int k = 0; k < 64; ++k) {
            int e = i + 16 * k;          // 0..1023
            int row = e >> 5, col = e & 31;
            m = fmaxf(m, base[row * 96 + col]);
        }
#pragma unroll
        for (int sh = 8; sh >= 1; sh >>= 1) m = fmaxf(m, __shfl_xor(m, sh));
        if (i == 0) p3[r] = m;
    }
    __syncthreads();
    if (tid < 30) {
        float v; int off;
        if (tid < 16) { v = p4[tid]; off = c * 16 + tid; }
        else if (tid < 25) { int q = tid - 16; v = p3[q]; off = 48 + c * 9 + q; }
        else if (tid < 29) {
            int q = tid - 25; int i2 = q >> 1, j2 = q & 1;
            v = fmaxf(fmaxf(p4[(2 * i2) * 4 + 2 * j2], p4[(2 * i2) * 4 + 2 * j2 + 1]),
                      fmaxf(p4[(2 * i2 + 1) * 4 + 2 * j2], p4[(2 * i2 + 1) * 4 + 2 * j2 + 1]));
            off = 75 + c * 4 + q;
        } else {
            float m = p4[0];
#pragma unroll
            for (int q = 1; q < 16; ++q) m = fmaxf(m, p4[q]);
            v = m; off = 87 + c;
        }
        out_pooled[(size_t)n * 90 + off] = v;
        ws_pooled[(size_t)n * 90 + off] = v;
    }
}

// ---------------- GEMM: Y(2048,4096) = relu(X(2048,90) @ W(4096,90)^T + b) ----------------
__global__ __launch_bounds__(256) void gemm90_kernel(const float* __restrict__ X,
                                                     const float* __restrict__ W,
                                                     const float* __restrict__ bias,
                                                     float* __restrict__ Y) {
    __shared__ __align__(16) float Xs[32][132];
    __shared__ __align__(16) float Ws[32][132];
    int tid = threadIdx.x;
    int R0 = blockIdx.x * 128, C0 = blockIdx.y * 128;
    int r0t = (tid >> 4) * 8, c0t = (tid & 15) * 8;
    float acc[8][8];
#pragma unroll
    for (int i = 0; i < 8; ++i)
#pragma unroll
        for (int j = 0; j < 8; ++j) acc[i][j] = 0.f;

    for (int k0 = 0; k0 < 96; k0 += 32) {
#pragma unroll
        for (int j = 0; j < 4; ++j) {
            int idx = tid + 256 * j;
            int row = idx & 127, q = idx >> 7;
            int kg = k0 + 4 * q;
            const float2* p = (const float2*)&X[(size_t)(R0 + row) * 90 + kg];
            float2 a = p[0], b = p[1];
            Xs[4 * q + 0][row] = a.x; Xs[4 * q + 1][row] = a.y;
            Xs[4 * q + 2][row] = b.x; Xs[4 * q + 3][row] = b.y;
        }
#pragma unroll
        for (int j = 0; j < 4; ++j) {
            int idx = tid + 256 * j;
            int col = idx & 127, q = idx >> 7;
            int kg = k0 + 4 * q;
            float v0, v1, v2, v3;
            if (kg + 3 < 90) {
                const float2* p = (const float2*)&W[(size_t)(C0 + col) * 90 + kg];
                float2 a = p[0], b = p[1];
                v0 = a.x; v1 = a.y; v2 = b.x; v3 = b.y;
            } else {
                const float* p = &W[(size_t)(C0 + col) * 90];
                v0 = (kg + 0 < 90) ? p[kg + 0] : 0.f;
                v1 = (kg + 1 < 90) ? p[kg + 1] : 0.f;
                v2 = (kg + 2 < 90) ? p[kg + 2] : 0.f;
                v3 = (kg + 3 < 90) ? p[kg + 3] : 0.f;
            }
            Ws[4 * q + 0][col] = v0; Ws[4 * q + 1][col] = v1;
            Ws[4 * q + 2][col] = v2; Ws[4 * q + 3][col] = v3;
        }
        __syncthreads();
#pragma unroll 8
        for (int kk = 0; kk < 32; ++kk) {
            float4 xa = *(const float4*)&Xs[kk][r0t];
            float4 xb = *(const float4*)&Xs[kk][r0t + 4];
            float4 wa = *(const float4*)&Ws[kk][c0t];
            float4 wb = *(const float4*)&Ws[kk][c0t + 4];
            float xr[8] = {xa.x, xa.y, xa.z, xa.w, xb.x, xb.y, xb.z, xb.w};
            float wc[8] = {wa.x, wa.y, wa.z, wa.w, wb.x, wb.y, wb.z, wb.w};
#pragma unroll
            for (int i = 0; i < 8; ++i)
#pragma unroll
                for (int j = 0; j < 8; ++j) acc[i][j] += xr[i] * wc[j];
        }
        __syncthreads();
    }
    float4 ba = *(const float4*)&bias[C0 + c0t];
    float4 bb = *(const float4*)&bias[C0 + c0t + 4];
    float bs[8] = {ba.x, ba.y, ba.z, ba.w, bb.x, bb.y, bb.z, bb.w};
#pragma unroll
    for (int i = 0; i < 8; ++i) {
        float4 o0, o1;
        o0.x = fmaxf(acc[i][0] + bs[0], 0.f); o0.y = fmaxf(acc[i][1] + bs[1], 0.f);
        o0.z = fmaxf(acc[i][2] + bs[2], 0.f); o0.w = fmaxf(acc[i][3] + bs[3], 0.f);
        o1.x = fmaxf(acc[i][4] + bs[4], 0.f); o1.y = fmaxf(acc[i][5] + bs[5], 0.f);
        o1.z = fmaxf(acc[i][6] + bs[6], 0.f); o1.w = fmaxf(acc[i][7] + bs[7], 0.f);
        *(float4*)&Y[(size_t)(R0 + r0t + i) * 4096 + C0 + c0t] = o0;
        *(float4*)&Y[(size_t)(R0 + r0t + i) * 4096 + C0 + c0t + 4] = o1;
    }
}

// ---------------- GEMM: acc(2048,64) += X(2048,4096) @ W(64,4096)^T, K-split + atomics ----------------
__global__ __launch_bounds__(256) void gemmk_kernel(const float* __restrict__ X,
                                                    const float* __restrict__ W,
                                                    float* __restrict__ acc_out) {
    __shared__ __align__(16) float Xs[32][132];
    __shared__ __align__(16) float Ws[32][68];
    int tid = threadIdx.x;
    int R0 = blockIdx.x * 128;
    int K0 = blockIdx.y * 256;
    int r0t = (tid >> 4) * 8, c0t = (tid & 15) * 4;
    float acc[8][4];
#pragma unroll
    for (int i = 0; i < 8; ++i)
#pragma unroll
        for (int j = 0; j < 4; ++j) acc[i][j] = 0.f;

    for (int k0 = K0; k0 < K0 + 256; k0 += 32) {
#pragma unroll
        for (int j = 0; j < 4; ++j) {
            int idx = tid + 256 * j;
            int row = idx & 127, q = idx >> 7;
            float4 a = *(const float4*)&X[(size_t)(R0 + row) * 4096 + k0 + 4 * q];
            Xs[4 * q + 0][row] = a.x; Xs[4 * q + 1][row] = a.y;
            Xs[4 * q + 2][row] = a.z; Xs[4 * q + 3][row] = a.w;
        }
#pragma unroll
        for (int j = 0; j < 2; ++j) {
            int idx = tid + 256 * j;
            int col = idx & 63, q = idx >> 6;
            float4 a = *(const float4*)&W[(size_t)col * 4096 + k0 + 4 * q];
            Ws[4 * q + 0][col] = a.x; Ws[4 * q + 1][col] = a.y;
            Ws[4 * q + 2][col] = a.z; Ws[4 * q + 3][col] = a.w;
        }
        __syncthreads();
#pragma unroll 8
        for (int kk = 0; kk < 32; ++kk) {
            float4 xa = *(const float4*)&Xs[kk][r0t];
            float4 xb = *(const float4*)&Xs[kk][r0t + 4];
            float4 wa = *(const float4*)&Ws[kk][c0t];
            float xr[8] = {xa.x, xa.y, xa.z, xa.w, xb.x, xb.y, xb.z, xb.w};
            float wc[4] = {wa.x, wa.y, wa.z, wa.w};
#pragma unroll
            for (int i = 0; i < 8; ++i)
#pragma unroll
                for (int j = 0; j < 4; ++j) acc[i][j] += xr[i] * wc[j];
        }
        __syncthreads();
    }
#pragma unroll
    for (int i = 0; i < 8; ++i)
#pragma unroll
        for (int j = 0; j < 4; ++j)
            atomicAdd(&acc_out[(size_t)(R0 + r0t + i) * 64 + c0t + j], acc[i][j]);
}

// ---------------- X1 = relu(acc1 + fc7_b) @ wih1^T + bih1 + bhh1  -> (2048,256) ----------------
__global__ __launch_bounds__(256) void x1_kernel(const float* __restrict__ acc1,
                                                 const float* __restrict__ fc7_b,
                                                 const float* __restrict__ wih1,
                                                 const float* __restrict__ bih1,
                                                 const float* __restrict__ bhh1,
                                                 float* __restrict__ X1) {
    __shared__ __align__(16) float xr[8][64];
    int tid = threadIdx.x;
    int R0 = blockIdx.x * 8;
#pragma unroll
    for (int j = 0; j < 2; ++j) {
        int idx = tid + 256 * j;
        int r = idx >> 6, k = idx & 63;
        xr[r][k] = fmaxf(acc1[(size_t)(R0 + r) * 64 + k] + fc7_b[k], 0.f);
    }
    __syncthreads();
    int u = tid;
    float w[64];
#pragma unroll
    for (int q = 0; q < 16; ++q) {
        float4 a = *(const float4*)&wih1[(size_t)u * 64 + 4 * q];
        w[4 * q] = a.x; w[4 * q + 1] = a.y; w[4 * q + 2] = a.z; w[4 * q + 3] = a.w;
    }
    float bias = bih1[u] + bhh1[u];
    for (int r = 0; r < 8; ++r) {
        float g = bias;
#pragma unroll
        for (int k = 0; k < 64; ++k) g += w[k] * xr[r][k];
        X1[(size_t)(R0 + r) * 256 + u] = g;
    }
}

// ---------------- sequential 2-layer LSTM; ONE WAVE per batch, software-pipelined ----------------
// At iteration t (entering: h1h holds h1(t); pa,pb = b2 + whh2·h2(t-1); xbuf holds X1 rows t+1,t+2):
//   read h1(t) ONCE -> feed BOTH L1-gates(t+1) and L2-h1-dots(t) as one interleaved
//   independent 192-dot2 block. L2 tail (shuffles, h2 cell, h2 publish, w2b dots for t+1)
//   has ~a full step of slack. Single-buffer LDS (one wave, in-order DS). 2-deep X1 prefetch.
__global__ __launch_bounds__(64, 1) void seq_kernel(const float* __restrict__ X1,
                                                    const float* __restrict__ whh1,
                                                    const float* __restrict__ wih2,
                                                    const float* __restrict__ whh2,
                                                    const float* __restrict__ bih2,
                                                    const float* __restrict__ bhh2,
                                                    float* __restrict__ h1_all, float* __restrict__ c1_all,
                                                    float* __restrict__ h2_all, float* __restrict__ c2_all) {
    __shared__ __align__(16) _Float16 h1h[64];
    __shared__ __align__(16) _Float16 h2h[32];
    const int l = threadIdx.x;          // 0..63
    const size_t n0 = (size_t)blockIdx.x * 256;

    // pack whh1 rows l, 64+l, 128+l, 192+l -> f16 pairs (i,f,g,o in-lane)
    h2f_t w1[4][32];
#pragma unroll
    for (int g = 0; g < 4; ++g) {
        const float* wr = whh1 + (size_t)(g * 64 + l) * 64;
#pragma unroll
        for (int q = 0; q < 32; ++q) w1[g][q] = h2pack(wr[2 * q], wr[2 * q + 1]);
    }
    // L2: rows l and 64+l of wih2 (128x64) and whh2 (128x32)
    h2f_t w2a[2][32], w2b[2][16];
#pragma unroll
    for (int g = 0; g < 2; ++g) {
        const float* wa = wih2 + (size_t)(g * 64 + l) * 64;
#pragma unroll
        for (int q = 0; q < 32; ++q) w2a[g][q] = h2pack(wa[2 * q], wa[2 * q + 1]);
        const float* wb = whh2 + (size_t)(g * 64 + l) * 32;
#pragma unroll
        for (int q = 0; q < 16; ++q) w2b[g][q] = h2pack(wb[2 * q], wb[2 * q + 1]);
    }
    const float b2a = bih2[l] + bhh2[l];
    const float b2b = bih2[64 + l] + bhh2[64 + l];

    const float* xp = X1 + n0 * 256;
    float c1, c2 = 0.f, pa, pb;
    // ---- prologue: t=0 state. h1(-1)=0, c1(-1)=0, h2(-1)=0, c2(-1)=0.
    {
        float a0 = xp[l], a1 = xp[64 + l], a2 = xp[128 + l], a3 = xp[192 + l];
        (void)a1;  // f-gate multiplies c1(-1)=0
        c1 = fsig(a0) * ftanh(a2);
        float h1n = fsig(a3) * ftanh(c1);
        h1h[l] = (_Float16)h1n;
        h1_all[n0 * 64 + l] = h1n;
        c1_all[n0 * 64 + l] = c1;
        pa = b2a; pb = b2b;   // whh2·h2(-1) = 0
    }
    lds_fence();
    // 2-deep X1 prefetch: xb0 = row 1 (for t=0), xb1 = row 2 (for t=1)
    float xb0[4], xb1[4];
    {
        const float* x1r = xp + 256;
        xb0[0] = x1r[l]; xb0[1] = x1r[64 + l]; xb0[2] = x1r[128 + l]; xb0[3] = x1r[192 + l];
        const float* x2r = xp + 512;
        xb1[0] = x2r[l]; xb1[1] = x2r[64 + l]; xb1[2] = x2r[128 + l]; xb1[3] = x2r[192 + l];
    }

#pragma unroll 2
    for (int t = 0; t < 256; ++t) {
        // read h1(t) once
        int4 hv[8];
        const int4* h1v = (const int4*)h1h;
#pragma unroll
        for (int q = 0; q < 8; ++q) hv[q] = h1v[q];
        // consume prefetched X1 row t+1, refill with row t+3 (clamped; tail values unused)
        float* xc = (t & 1) ? xb1 : xb0;
        float a0 = xc[0], a1 = xc[1], a2 = xc[2], a3 = xc[3];
        {
            int tr = (t + 3 < 256) ? (t + 3) : 255;
            const float* xq = xp + (size_t)tr * 256;
            xc[0] = xq[l]; xc[1] = xq[64 + l]; xc[2] = xq[128 + l]; xc[3] = xq[192 + l];
        }
        // interleaved independent dot block: L1 gates(t+1) [128] + L2 h1-part(t) [64]
#pragma unroll
        for (int q = 0; q < 8; ++q) {
            int4 v = hv[q];
            h2f_t hh0 = h2bits(v.x), hh1 = h2bits(v.y), hh2 = h2bits(v.z), hh3 = h2bits(v.w);
            a0 = fdot2(w1[0][4 * q], hh0, a0); a1 = fdot2(w1[1][4 * q], hh0, a1);
            a2 = fdot2(w1[2][4 * q], hh0, a2); a3 = fdot2(w1[3][4 * q], hh0, a3);
            pa = fdot2(w2a[0][4 * q], hh0, pa); pb = fdot2(w2a[1][4 * q], hh0, pb);
            a0 = fdot2(w1[0][4 * q + 1], hh1, a0); a1 = fdot2(w1[1][4 * q + 1], hh1, a1);
            a2 = fdot2(w1[2][4 * q + 1], hh1, a2); a3 = fdot2(w1[3][4 * q + 1], hh1, a3);
            pa = fdot2(w2a[0][4 * q + 1], hh1, pa); pb = fdot2(w2a[1][4 * q + 1], hh1, pb);
            a0 = fdot2(w1[0][4 * q + 2], hh2, a0); a1 = fdot2(w1[1][4 * q + 2], hh2, a1);
            a2 = fdot2(w1[2][4 * q + 2], hh2, a2); a3 = fdot2(w1[3][4 * q + 2], hh2, a3);
            pa = fdot2(w2a[0][4 * q + 2], hh2, pa); pb = fdot2(w2a[1][4 * q + 2], hh2, pb);
            a0 = fdot2(w1[0][4 * q + 3], hh3, a0); a1 = fdot2(w1[1][4 * q + 3], hh3, a1);
            a2 = fdot2(w1[2][4 * q + 3], hh3, a2); a3 = fdot2(w1[3][4 * q + 3], hh3, a3);
            pa = fdot2(w2a[0][4 * q + 3], hh3, pa); pb = fdot2(w2a[1][4 * q + 3], hh3, pb);
        }
        // ---- L2 tail for step t (off critical path)
        float gf_ = __shfl(pa, (l & 31) + 32);
        float go_ = __shfl(pb, (l & 31) + 32);
        if (l < 32) {
            c2 = fsig(gf_) * c2 + fsig(pa) * ftanh(pb);
            float h2n = fsig(go_) * ftanh(c2);
            h2h[l] = (_Float16)h2n;
            h2_all[(n0 + t) * 32 + l] = h2n;
            c2_all[(n0 + t) * 32 + l] = c2;
        }
        lds_fence();
        // ---- L1 cell for step t+1 (critical path; overlaps L2 tail in the scheduler)
        c1 = fsig(a1) * c1 + fsig(a0) * ftanh(a2);
        float h1n = fsig(a3) * ftanh(c1);
        h1h[l] = (_Float16)h1n;
        if (t < 255) {
            h1_all[(n0 + t + 1) * 64 + l] = h1n;
            c1_all[(n0 + t + 1) * 64 + l] = c1;
        }
        // ---- h2-part dots for step t+1 (reads h2(t) just published)
        pa = b2a; pb = b2b;
        const int4* h2v = (const int4*)h2h;
#pragma unroll
        for (int q = 0; q < 4; ++q) {
            int4 v = h2v[q];
            h2f_t hh0 = h2bits(v.x), hh1 = h2bits(v.y), hh2 = h2bits(v.z), hh3 = h2bits(v.w);
            pa = fdot2(w2b[0][4 * q], hh0, pa); pb = fdot2(w2b[1][4 * q], hh0, pb);
            pa = fdot2(w2b[0][4 * q + 1], hh1, pa); pb = fdot2(w2b[1][4 * q + 1], hh1, pb);
            pa = fdot2(w2b[0][4 * q + 2], hh2, pa); pb = fdot2(w2b[1][4 * q + 2], hh2, pb);
            pa = fdot2(w2b[0][4 * q + 3], hh3, pa); pb = fdot2(w2b[1][4 * q + 3], hh3, pb);
        }
        lds_fence();   // h1(t+1) visible before next iteration's read
    }
}

// ---------------- fpool + progress (parallel over all 2048 rows) ----------------
__global__ __launch_bounds__(256) void fpool_kernel(const float* __restrict__ h2_all,
                                                    const float* __restrict__ fw,
                                                    const float* __restrict__ fb,
                                                    const float* __restrict__ fc8_w,
                                                    const float* __restrict__ fc8_b,
                                                    float* __restrict__ fpool_ws,
                                                    float* __restrict__ out_fpooled,
                                                    float* __restrict__ out_progress) {
    __shared__ __align__(16) float h2t[16][32];
    __shared__ float fwl[2880];
    int tid = threadIdx.x;
    int R0 = blockIdx.x * 16;
#pragma unroll
    for (int j = 0; j < 2; ++j) {
        int idx = tid + 256 * j;
        int r = idx >> 5, k = idx & 31;
        h2t[r][k] = h2_all[(size_t)(R0 + r) * 32 + k];
    }
    for (int idx = tid; idx < 2880; idx += 256) fwl[idx] = fw[idx];
    __syncthreads();
    for (int j = 0; j < 6; ++j) {
        int idx = tid + 256 * j;
        if (idx < 1440) {
            int r = idx / 90, cc = idx % 90;
            float g = fb[cc];
#pragma unroll
            for (int k = 0; k < 32; ++k) g += h2t[r][k] * fwl[cc * 32 + k];
            fpool_ws[(size_t)(R0 + r) * 90 + cc] = g;
            out_fpooled[(size_t)(R0 + r) * 90 + cc] = g;
        }
    }
    if (tid < 16) {
        float g = fc8_b[0];
#pragma unroll
        for (int k = 0; k < 32; ++k) g += h2t[tid][k] * fc8_w[k];
        out_progress[R0 + tid] = fsig(g);
    }
}

// ---------------- forecast LSTM cells + fprogress (parallel over all 2048 rows) ----------------
__global__ __launch_bounds__(256) void fh_kernel(const float* __restrict__ acc2,
                                                 const float* __restrict__ fc7_b,
                                                 const float* __restrict__ h1_all,
                                                 const float* __restrict__ c1_all,
                                                 const float* __restrict__ h2_all,
                                                 const float* __restrict__ c2_all,
                                                 const float* __restrict__ wih1,
                                                 const float* __restrict__ whh1,
                                                 const float* __restrict__ bih1,
                                                 const float* __restrict__ bhh1,
                                                 const float* __restrict__ wih2,
                                                 const float* __restrict__ whh2,
                                                 const float* __restrict__ bih2,
                                                 const float* __restrict__ bhh2,
                                                 const float* __restrict__ fc8_w,
                                                 const float* __restrict__ fc8_b,
                                                 float* __restrict__ out_fprog) {
    __shared__ __align__(16) float xcat[8][128];   // [fe2 | h1]
    __shared__ float g1f[8][256];
    __shared__ __align__(16) float x2c[8][96];     // [fh1 | h2]
    __shared__ float g2f[8][128];
    __shared__ __align__(16) float fh2s[8][32];
    int tid = threadIdx.x;
    int R0 = blockIdx.x * 8;
#pragma unroll
    for (int j = 0; j < 4; ++j) {
        int idx = tid + 256 * j;
        int r = idx >> 7, k = idx & 127;
        float v;
        if (k < 64) v = fmaxf(acc2[(size_t)(R0 + r) * 64 + k] + fc7_b[k], 0.f);
        else v = h1_all[(size_t)(R0 + r) * 64 + (k - 64)];
        xcat[r][k] = v;
    }
    {
        int r = tid >> 5, k = tid & 31;
        x2c[r][64 + k] = h2_all[(size_t)(R0 + r) * 32 + k];
    }
    __syncthreads();
    {   // gates1f: 256 units, thread per unit, 8 rows
        int u = tid;
        float wa[64], wb[64];
#pragma unroll
        for (int q = 0; q < 16; ++q) {
            float4 a = *(const float4*)&wih1[(size_t)u * 64 + 4 * q];
            wa[4 * q] = a.x; wa[4 * q + 1] = a.y; wa[4 * q + 2] = a.z; wa[4 * q + 3] = a.w;
            float4 b = *(const float4*)&whh1[(size_t)u * 64 + 4 * q];
            wb[4 * q] = b.x; wb[4 * q + 1] = b.y; wb[4 * q + 2] = b.z; wb[4 * q + 3] = b.w;
        }
        float bias = bih1[u] + bhh1[u];
        for (int r = 0; r < 8; ++r) {
            float g = bias;
#pragma unroll
            for (int k = 0; k < 64; ++k) g += wa[k] * xcat[r][k];
#pragma unroll
            for (int k = 0; k < 64; ++k) g += wb[k] * xcat[r][64 + k];
            g1f[r][u] = g;
        }
    }
    __syncthreads();
#pragma unroll
    for (int j = 0; j < 2; ++j) {   // fh1 elementwise: 512 tasks
        int idx = tid + 256 * j;
        int r = idx >> 6, h = idx & 63;
        float gi = g1f[r][h], gf = g1f[r][64 + h], gg = g1f[r][128 + h], go = g1f[r][192 + h];
        float c1v = c1_all[(size_t)(R0 + r) * 64 + h];
        float c = fsig(gf) * c1v + fsig(gi) * ftanh(gg);
        x2c[r][h] = fsig(go) * ftanh(c);
    }
    __syncthreads();
    {   // gates2f: 128 units x 8 rows
        int u = tid & 127;
        int rb = (tid >> 7) * 4;
        float wa[64], wb2[32];
#pragma unroll
        for (int q = 0; q < 16; ++q) {
            float4 a = *(const float4*)&wih2[(size_t)u * 64 + 4 * q];
            wa[4 * q] = a.x; wa[4 * q + 1] = a.y; wa[4 * q + 2] = a.z; wa[4 * q + 3] = a.w;
        }
#pragma unroll
        for (int q = 0; q < 8; ++q) {
            float4 b = *(const float4*)&whh2[(size_t)u * 32 + 4 * q];
            wb2[4 * q] = b.x; wb2[4 * q + 1] = b.y; wb2[4 * q + 2] = b.z; wb2[4 * q + 3] = b.w;
        }
        float bias = bih2[u] + bhh2[u];
        for (int r = rb; r < rb + 4; ++r) {
            float g = bias;
#pragma unroll
            for (int k = 0; k < 64; ++k) g += wa[k] * x2c[r][k];
#pragma unroll
            for (int k = 0; k < 32; ++k) g += wb2[k] * x2c[r][64 + k];
            g2f[r][u] = g;
        }
    }
    __syncthreads();
    {   // fh2 elementwise: 256 tasks
        int r = tid >> 5, v = tid & 31;
        float gi = g2f[r][v], gf = g2f[r][32 + v], gg = g2f[r][64 + v], go = g2f[r][96 + v];
        float c2v = c2_all[(size_t)(R0 + r) * 32 + v];
        float c = fsig(gf) * c2v + fsig(gi) * ftanh(gg);
        fh2s[r][v] = fsig(go) * ftanh(c);
    }
    __syncthreads();
    if (tid < 8) {
        float g = fc8_b[0];
#pragma unroll
        for (int k = 0; k < 32; ++k) g += fh2s[tid][k] * fc8_w[k];
        out_fprog[R0 + tid] = fsig(g);
    }
}

// ---------------- launch ----------------
extern "C" void kernel_launch(void* const* d_in, const int* in_sizes, int n_in,
                              void* d_out, int out_size, void* d_ws, size_t ws_size,
                              hipStream_t stream) {
    (void)in_sizes; (void)n_in; (void)out_size; (void)ws_size;
    const float* frames   = (const float*)d_in[0];
    const float* spp_fc_w = (const float*)d_in[1];
    const float* spp_fc_b = (const float*)d_in[2];
    const float* fc7_w    = (const float*)d_in[3];
    const float* fc7_b    = (const float*)d_in[4];
    const float* l1_wih   = (const float*)d_in[5];
    const float* l1_whh   = (const float*)d_in[6];
    const float* l1_bih   = (const float*)d_in[7];
    const float* l1_bhh   = (const float*)d_in[8];
    const float* l2_wih   = (const float*)d_in[9];
    const float* l2_whh   = (const float*)d_in[10];
    const float* l2_bih   = (const float*)d_in[11];
    const float* l2_bhh   = (const float*)d_in[12];
    const float* fo_w     = (const float*)d_in[13];
    const float* fo_b     = (const float*)d_in[14];
    const float* fc8_w    = (const float*)d_in[15];
    const float* fc8_b    = (const float*)d_in[16];
    float* out = (float*)d_out;
    float* ws  = (float*)d_ws;

    float* pooled = ws + OFF_POOLED;
    float* emb1   = ws + OFF_EMB1;
    float* acc1   = ws + OFF_ACC1;
    float* acc2   = ws + OFF_ACC2;
    float* X1     = ws + OFF_X1;
    float* fpool  = ws + OFF_FPOOL;
    float* h1a    = ws + OFF_H1;
    float* c1a    = ws + OFF_C1;
    float* h2a    = ws + OFF_H2;
    float* c2a    = ws + OFF_C2;

    float* out_prog    = out;
    float* out_fprog   = out + 2048;
    float* out_pooled  = out + 4096;
    float* out_fpooled = out + 188416;

    hipMemsetAsync(acc1, 0, (size_t)262144 * sizeof(float), stream);  // acc1+acc2 contiguous
    spp_kernel<<<6144, 256, 0, stream>>>(frames, out_pooled, pooled);
    gemm90_kernel<<<dim3(16, 32), 256, 0, stream>>>(pooled, spp_fc_w, spp_fc_b, emb1);
    gemmk_kernel<<<dim3(16, 16), 256, 0, stream>>>(emb1, fc7_w, acc1);
    x1_kernel<<<256, 256, 0, stream>>>(acc1, fc7_b, l1_wih, l1_bih, l1_bhh, X1);
    seq_kernel<<<8, 64, 0, stream>>>(X1, l1_whh, l2_wih, l2_whh, l2_bih, l2_bhh, h1a, c1a, h2a, c2a);
    fpool_kernel<<<128, 256, 0, stream>>>(h2a, fo_w, fo_b, fc8_w, fc8_b, fpool, out_fpooled, out_prog);
    gemm90_kernel<<<dim3(16, 32), 256, 0, stream>>>(fpool, spp_fc_w, spp_fc_b, emb1);
    gemmk_kernel<<<dim3(16, 16), 256, 0, stream>>>(emb1, fc7_w, acc2);
    fh_kernel<<<256, 256, 0, stream>>>(acc2, fc7_b, h1a, c1a, h2a, c2a,
                                       l1_wih, l1_whh, l1_bih, l1_bhh,
                                       l2_wih, l2_whh, l2_bih, l2_bhh,
                                       fc8_w, fc8_b, out_fprog);
}